// Round 1
// baseline (979.585 us; speedup 1.0000x reference)
//
#include <hip/hip_runtime.h>
#include <hip/hip_bf16.h>

#define BF16 __hip_bfloat16

typedef __bf16 bf16x8 __attribute__((ext_vector_type(8)));
typedef float  f32x4  __attribute__((ext_vector_type(4)));
typedef float  f32x16 __attribute__((ext_vector_type(16)));

__device__ inline void gload_lds16(const void* g, void* s) {
  __builtin_amdgcn_global_load_lds(
      (const __attribute__((address_space(1))) unsigned int*)g,
      (__attribute__((address_space(3))) unsigned int*)s, 16, 0, 0);
}

__device__ inline float gelu_erf(float x) {
  return 0.5f * x * (1.0f + erff(x * 0.70710678118654752f));
}

// ---------------- cast kernels ----------------
__global__ void cast_x_kernel(const float* __restrict__ in, BF16* __restrict__ out, int n4) {
  int i = blockIdx.x * 256 + threadIdx.x;
  if (i >= n4) return;
  float4 v = ((const float4*)in)[i];
  union { BF16 h[4]; uint2 u; } t;
  t.h[0] = __float2bfloat16(v.x); t.h[1] = __float2bfloat16(v.y);
  t.h[2] = __float2bfloat16(v.z); t.h[3] = __float2bfloat16(v.w);
  ((uint2*)out)[i] = t.u;
}

struct WPtrs { const float* p[9]; };

__global__ void cast_w_kernel(WPtrs wp, BF16* __restrict__ out) {
  int i = blockIdx.x * 256 + threadIdx.x;   // < 9*65536
  int seg = i >> 16, off = i & 65535;
  out[i] = __float2bfloat16(wp.p[seg][off]);
}

// W~[p, h*32+d] = sum_j mix_w[p, h*32+j] * latent_q[h*32+j, d]
__global__ void build_wtilde(const float* __restrict__ mixw, const float* __restrict__ lq,
                             BF16* __restrict__ wt) {
  int p = blockIdx.x, c = threadIdx.x;
  int h = c >> 5, d = c & 31;
  float s = 0.f;
#pragma unroll
  for (int j = 0; j < 32; ++j)
    s += mixw[p * 256 + h * 32 + j] * lq[(h * 32 + j) * 32 + d];
  wt[p * 256 + c] = __float2bfloat16(s);
}

// ---------------- GEMM: out = X(R,256) @ W(256,256)^T  (+epilogue) ----------------
// MODE 0: raw f32 out     MODE 1: bias+gelu+residual -> bf16
// MODE 2: bias+residual -> bf16      MODE 3: bias -> f32
template <int MODE>
__global__ __launch_bounds__(256) void gemm256(
    const BF16* __restrict__ X, const BF16* __restrict__ W,
    const float* __restrict__ bias, const BF16* __restrict__ RES,
    void* __restrict__ OUTp, int R) {
  __shared__ __align__(16) BF16 As[128 * 32];
  __shared__ __align__(16) BF16 Bs[128 * 32];
  const int bid = blockIdx.x;
  const int rb = bid >> 1, cb = bid & 1;
  const int r0 = rb << 7;
  const int tid = threadIdx.x;
  const int wid = tid >> 6, lane = tid & 63;
  const int wr = wid >> 1, wc = wid & 1;
  const int fr = lane & 15, fq = lane >> 4;

  f32x4 acc[4][4];
#pragma unroll
  for (int m = 0; m < 4; ++m)
#pragma unroll
    for (int n = 0; n < 4; ++n)
#pragma unroll
      for (int j = 0; j < 4; ++j) acc[m][n][j] = 0.f;

  const BF16* Xg = X + (size_t)r0 * 256;
  const BF16* Wg = W + (size_t)(cb * 128) * 256;

  for (int kt = 0; kt < 8; ++kt) {
    const int k0 = kt * 32;
#pragma unroll
    for (int i = 0; i < 2; ++i) {
      int c = i * 256 + wid * 64 + lane;
      gload_lds16(Xg + (size_t)(c >> 2) * 256 + (k0 + (c & 3) * 8),
                  &As[(i * 256 + wid * 64) * 8]);
    }
#pragma unroll
    for (int i = 0; i < 2; ++i) {
      int c = i * 256 + wid * 64 + lane;
      gload_lds16(Wg + (size_t)(c >> 2) * 256 + (k0 + (c & 3) * 8),
                  &Bs[(i * 256 + wid * 64) * 8]);
    }
    __syncthreads();
    bf16x8 af[4], bv[4];
#pragma unroll
    for (int m = 0; m < 4; ++m)
      af[m] = *(const bf16x8*)&As[(wr * 64 + m * 16 + fr) * 32 + fq * 8];
#pragma unroll
    for (int n = 0; n < 4; ++n)
      bv[n] = *(const bf16x8*)&Bs[(wc * 64 + n * 16 + fr) * 32 + fq * 8];
#pragma unroll
    for (int m = 0; m < 4; ++m)
#pragma unroll
      for (int n = 0; n < 4; ++n)
        acc[m][n] = __builtin_amdgcn_mfma_f32_16x16x32_bf16(af[m], bv[n], acc[m][n], 0, 0, 0);
    __syncthreads();
  }

  const int colbase = cb * 128 + wc * 64;
#pragma unroll
  for (int n = 0; n < 4; ++n) {
    const int col = colbase + n * 16 + fr;
    float bval = 0.f;
    if (MODE != 0) bval = bias[col];
#pragma unroll
    for (int m = 0; m < 4; ++m) {
#pragma unroll
      for (int j = 0; j < 4; ++j) {
        const int row = r0 + wr * 64 + m * 16 + fq * 4 + j;
        const size_t idx = (size_t)row * 256 + col;
        float u = acc[m][n][j];
        if (MODE == 0) {
          ((float*)OUTp)[idx] = u;
        } else if (MODE == 3) {
          ((float*)OUTp)[idx] = u + bval;
        } else {
          float g = u + bval;
          if (MODE == 1) g = gelu_erf(g);
          float res = __bfloat162float(RES[idx]);
          ((BF16*)OUTp)[idx] = __float2bfloat16(res + g);
        }
      }
    }
  }
}

// ---------------- softmax-over-N stats (two stage, deterministic) ----------------
__global__ void softmax_stats(const float* __restrict__ mixed,
                              float* __restrict__ pm, float* __restrict__ ps) {
  int ci = blockIdx.x, t = threadIdx.x;       // ci: 512 chunks of 256 rows
  size_t base = (size_t)ci * 65536 + t;
  float m = -3.0e38f, s = 0.f;
  for (int i = 0; i < 256; ++i) {
    float x = mixed[base + (size_t)i * 256];
    float mn = fmaxf(m, x);
    s = s * __expf(m - mn) + __expf(x - mn);
    m = mn;
  }
  pm[ci * 256 + t] = m;
  ps[ci * 256 + t] = s;
}

__global__ void softmax_merge(const float* __restrict__ pm, const float* __restrict__ ps,
                              float* __restrict__ Mf, float* __restrict__ Sf) {
  int b = blockIdx.x, t = threadIdx.x;
  float m = -3.0e38f, s = 0.f;
  for (int c = 0; c < 128; ++c) {
    float m2 = pm[(b * 128 + c) * 256 + t];
    float s2 = ps[(b * 128 + c) * 256 + t];
    float mn = fmaxf(m, m2);
    s = s * __expf(m - mn) + s2 * __expf(m2 - mn);
    m = mn;
  }
  Mf[b * 256 + t] = m;
  Sf[b * 256 + t] = 1.f / s;
}

// ---------------- z = enc @ v, MFMA over n-chunks, per-head 32x32 ----------------
// zpart[ci][h][m][d] = sum_{n in chunk} exp(mixed[n, h*32+m]-M) * v[n, h*32+d]
__global__ __launch_bounds__(256) void z_partial_mfma(
    const float* __restrict__ mixed, const BF16* __restrict__ v,
    const float* __restrict__ Mf, float* __restrict__ zpart) {
  int ci = blockIdx.x;                 // B*64 blocks, 512 rows each
  int b = ci >> 6, ch = ci & 63;
  int tid = threadIdx.x, wid = tid >> 6, lane = tid & 63;
  int l31 = lane & 31, kh = lane >> 5;
  size_t n0 = (size_t)b * 32768 + ch * 512;
  for (int hi = 0; hi < 2; ++hi) {
    int h = wid * 2 + hi;
    int col = h * 32 + l31;
    float Mp = Mf[b * 256 + col];
    f32x16 acc;
#pragma unroll
    for (int r = 0; r < 16; ++r) acc[r] = 0.f;
    for (int s = 0; s < 32; ++s) {     // K=16 rows per MFMA
      bf16x8 ea, vb;
      size_t nbase = n0 + s * 16 + kh * 8;
#pragma unroll
      for (int j = 0; j < 8; ++j) {
        float x = __expf(mixed[(nbase + j) * 256 + col] - Mp);
        ea[j] = (__bf16)x;
        vb[j] = *(const __bf16*)&v[(nbase + j) * 256 + col];
      }
      acc = __builtin_amdgcn_mfma_f32_32x32x16_bf16(ea, vb, acc, 0, 0, 0);
    }
    float* zp = zpart + (size_t)ci * 8192 + h * 1024;
#pragma unroll
    for (int reg = 0; reg < 16; ++reg) {
      int m = (reg & 3) + 8 * (reg >> 2) + 4 * kh;
      zp[m * 32 + l31] = acc[reg];
    }
  }
}

__global__ void z_merge(const float* __restrict__ zpart, const float* __restrict__ Sf,
                        float* __restrict__ z) {
  int i = blockIdx.x * 256 + threadIdx.x;   // [0, 4*8192)
  int b = i >> 13, j = i & 8191;
  int p = j >> 5;                           // h*32 + m
  float s = 0.f;
  for (int c = 0; c < 64; ++c) s += zpart[(size_t)(b * 64 + c) * 8192 + j];
  z[i] = s * Sf[b * 256 + p];
}

// ---------------- o = dec^T @ z  (row-local softmax over m, MFMA batch of 32 rows) ----
__global__ __launch_bounds__(256) void decode_o_mfma(
    const float* __restrict__ mixed, const float* __restrict__ z,
    BF16* __restrict__ o) {
  int ci = blockIdx.x;                 // B*64 blocks, 512 rows each
  int b = ci >> 6, ch = ci & 63;
  int tid = threadIdx.x, wid = tid >> 6, lane = tid & 63;
  int l31 = lane & 31, kh = lane >> 5;
  size_t rowbase = (size_t)b * 32768 + ch * 512;
  for (int hi = 0; hi < 2; ++hi) {
    int h = wid * 2 + hi;
    bf16x8 zf[2];
#pragma unroll
    for (int ks = 0; ks < 2; ++ks)
#pragma unroll
      for (int j = 0; j < 8; ++j)
        zf[ks][j] = (__bf16)z[b * 8192 + h * 1024 + (ks * 16 + kh * 8 + j) * 32 + l31];
    for (int s = 0; s < 16; ++s) {     // 32 output rows per step
      size_t n = rowbase + s * 32 + l31;
      const float* mrow = mixed + n * 256 + h * 32;
      float xv[16];
#pragma unroll
      for (int ks = 0; ks < 2; ++ks) {
        float4 a  = *(const float4*)(mrow + ks * 16 + kh * 8);
        float4 c4 = *(const float4*)(mrow + ks * 16 + kh * 8 + 4);
        xv[ks * 8 + 0] = a.x;  xv[ks * 8 + 1] = a.y;  xv[ks * 8 + 2] = a.z;  xv[ks * 8 + 3] = a.w;
        xv[ks * 8 + 4] = c4.x; xv[ks * 8 + 5] = c4.y; xv[ks * 8 + 6] = c4.z; xv[ks * 8 + 7] = c4.w;
      }
      float mx = xv[0];
#pragma unroll
      for (int i = 1; i < 16; ++i) mx = fmaxf(mx, xv[i]);
      mx = fmaxf(mx, __shfl_xor(mx, 32));
      float sm = 0.f, ev[16];
#pragma unroll
      for (int i = 0; i < 16; ++i) { ev[i] = __expf(xv[i] - mx); sm += ev[i]; }
      sm += __shfl_xor(sm, 32);
      float inv = 1.f / sm;
      bf16x8 af[2];
#pragma unroll
      for (int ks = 0; ks < 2; ++ks)
#pragma unroll
        for (int j = 0; j < 8; ++j) af[ks][j] = (__bf16)(ev[ks * 8 + j] * inv);
      f32x16 acc;
#pragma unroll
      for (int r = 0; r < 16; ++r) acc[r] = 0.f;
      acc = __builtin_amdgcn_mfma_f32_32x32x16_bf16(af[0], zf[0], acc, 0, 0, 0);
      acc = __builtin_amdgcn_mfma_f32_32x32x16_bf16(af[1], zf[1], acc, 0, 0, 0);
#pragma unroll
      for (int reg = 0; reg < 16; ++reg) {
        int nr = (reg & 3) + 8 * (reg >> 2) + 4 * kh;
        o[(rowbase + s * 32 + nr) * 256 + h * 32 + l31] = __float2bfloat16(acc[reg]);
      }
    }
  }
}

// ---------------- launch ----------------
extern "C" void kernel_launch(void* const* d_in, const int* in_sizes, int n_in,
                              void* d_out, int out_size, void* d_ws, size_t ws_size,
                              hipStream_t stream) {
  const float* x     = (const float*)d_in[0];
  const float* lq    = (const float*)d_in[1];
  const float* kfc1w = (const float*)d_in[2];
  const float* kfc1b = (const float*)d_in[3];
  const float* kfcsw = (const float*)d_in[4];
  const float* kfcsb = (const float*)d_in[5];
  const float* kfc2w = (const float*)d_in[6];
  const float* kfc2b = (const float*)d_in[7];
  const float* vfc1w = (const float*)d_in[8];
  const float* vfc1b = (const float*)d_in[9];
  const float* vfcsw = (const float*)d_in[10];
  const float* vfcsb = (const float*)d_in[11];
  const float* vfc2w = (const float*)d_in[12];
  const float* vfc2b = (const float*)d_in[13];
  const float* mixw  = (const float*)d_in[14];
  const float* outw  = (const float*)d_in[15];
  const float* outb  = (const float*)d_in[16];

  const int R = in_sizes[0] / 256;          // 131072 rows total (B*N)

  char* ws = (char*)d_ws;
  BF16*  x_bf  = (BF16*)(ws);                    //  67,108,864 B
  BF16*  b1    = (BF16*)(ws + 67108864);         //  67,108,864 B
  BF16*  b2    = (BF16*)(ws + 134217728);        //  67,108,864 B
  BF16*  wbf   = (BF16*)(ws + 201326592);        //   1,179,648 B (9 x 256x256 bf16)
  BF16*  wt    = (BF16*)(ws + 202506240);        //     131,072 B
  float* pm    = (float*)(ws + 202637312);       //     524,288 B
  float* ps    = (float*)(ws + 203161600);       //     524,288 B
  float* Mf    = (float*)(ws + 203685888);       //       4,096 B
  float* Sf    = (float*)(ws + 203689984);       //       4,096 B
  float* zpart = (float*)(ws + 203694080);       //   8,388,608 B
  float* z     = (float*)(ws + 212082688);       //     131,072 B
  float* mixed = (float*)d_out;                  // d_out doubles as mixed (f32, 134MB)

  // 1) casts + fused score/mix weight
  cast_x_kernel<<<32768, 256, 0, stream>>>(x, x_bf, in_sizes[0] / 4);
  WPtrs wp = {{kfc1w, kfcsw, kfcsw + 65536, kfc2w, vfc1w, vfcsw, vfcsw + 65536, vfc2w, outw}};
  cast_w_kernel<<<2304, 256, 0, stream>>>(wp, wbf);
  build_wtilde<<<256, 256, 0, stream>>>(mixw, lq, wt);

  const int G = (R / 128) * 2;   // 2048 blocks per GEMM

  // 2) k = ResidualMLP(x)   x_bf -> b1 -> b2 -> b1 -> b2
  gemm256<1><<<G, 256, 0, stream>>>(x_bf, wbf + 0,      kfc1b,       x_bf, b1, R);
  gemm256<1><<<G, 256, 0, stream>>>(b1,   wbf + 65536,  kfcsb,       b1,   b2, R);
  gemm256<1><<<G, 256, 0, stream>>>(b2,   wbf + 131072, kfcsb + 256, b2,   b1, R);
  gemm256<2><<<G, 256, 0, stream>>>(b1,   wbf + 196608, kfc2b,       b1,   b2, R);

  // 3) mixed = k @ Wtilde^T  (f32, into d_out)
  gemm256<0><<<G, 256, 0, stream>>>(b2, wt, nullptr, nullptr, (void*)mixed, R);

  // 4) softmax-over-N stats
  softmax_stats<<<512, 256, 0, stream>>>(mixed, pm, ps);
  softmax_merge<<<4, 256, 0, stream>>>(pm, ps, Mf, Sf);

  // 5) v = ResidualMLP(x)   x_bf -> b1 -> b2 -> b1 -> b2   (k no longer needed)
  gemm256<1><<<G, 256, 0, stream>>>(x_bf, wbf + 262144, vfc1b,       x_bf, b1, R);
  gemm256<1><<<G, 256, 0, stream>>>(b1,   wbf + 327680, vfcsb,       b1,   b2, R);
  gemm256<1><<<G, 256, 0, stream>>>(b2,   wbf + 393216, vfcsb + 256, b2,   b1, R);
  gemm256<2><<<G, 256, 0, stream>>>(b1,   wbf + 458752, vfc2b,       b1,   b2, R);

  // 6) z = enc @ v (partials over 64 n-chunks, then merge+normalize)
  z_partial_mfma<<<256, 256, 0, stream>>>(mixed, b2, Mf, zpart);
  z_merge<<<128, 256, 0, stream>>>(zpart, Sf, z);

  // 7) o = dec^T @ z  -> bf16 into b1
  decode_o_mfma<<<256, 256, 0, stream>>>(mixed, z, b1);

  // 8) out = o @ out_w^T + out_b  (f32 into d_out, overwrites mixed)
  gemm256<3><<<G, 256, 0, stream>>>(b1, wbf + 524288, outb, nullptr, d_out, R);
}

// Round 2
// 897.219 us; speedup vs baseline: 1.0918x; 1.0918x over previous
//
#include <hip/hip_runtime.h>
#include <hip/hip_bf16.h>
#include <math.h>

#define BF16 __hip_bfloat16

typedef __bf16 bf16x8 __attribute__((ext_vector_type(8)));
typedef float  f32x4  __attribute__((ext_vector_type(4)));
typedef float  f32x16 __attribute__((ext_vector_type(16)));

__device__ inline float gelu_erf(float x) {
  return 0.5f * x * (1.0f + erff(x * 0.70710678118654752f));
}

struct WPtrs { const float* p[9]; };
struct FArgs { const BF16* w[5]; const float* b[5]; };

// ---------------- small prep kernels ----------------
__global__ void cast_w_kernel(WPtrs wp, BF16* __restrict__ out) {
  int i = blockIdx.x * 256 + threadIdx.x;   // < 9*65536
  int seg = i >> 16, off = i & 65535;
  out[i] = __float2bfloat16(wp.p[seg][off]);
}

// W~[p, h*32+d] = sum_j mix_w[p, h*32+j] * latent_q[h*32+j, d]
__global__ void build_wtilde(const float* __restrict__ mixw, const float* __restrict__ lq,
                             BF16* __restrict__ wt) {
  int p = blockIdx.x, c = threadIdx.x;
  int h = c >> 5, d = c & 31;
  float s = 0.f;
#pragma unroll
  for (int j = 0; j < 32; ++j)
    s += mixw[p * 256 + h * 32 + j] * lq[(h * 32 + j) * 32 + d];
  wt[p * 256 + c] = __float2bfloat16(s);
}

// ---------------- fused resident-tile MLP ----------------
// VARIANT 0: k-MLP(4 layers) + mixed(=k@Wt^T, f32 out) + softmax-N partial stats
// VARIANT 1: v-MLP(4 layers) -> bf16 global
// VARIANT 2: final projection (1 layer, bias, f32 out)
// act tile: 128 rows x 256 cols bf16, XOR-swizzled (byte ^= (row&7)<<4 on 16B granules)
template <int VARIANT>
__global__ __launch_bounds__(256, 2) void fused_mlp(
    const float* __restrict__ xin, const BF16* __restrict__ oin, FArgs args,
    float* __restrict__ fout, BF16* __restrict__ bout,
    float* __restrict__ pm, float* __restrict__ ps) {
  __shared__ __align__(16) char act[128 * 512];
  const int tid = threadIdx.x;
  const int blk = blockIdx.x;
  const int wid = tid >> 6, lane = tid & 63;
  const int wr = wid >> 1, wc = wid & 1;
  const int fr = lane & 15, fq = lane >> 4;
  const size_t row0 = (size_t)blk * 128;

  // ---- stage input tile into swizzled LDS ----
  if (VARIANT != 2) {
    const float* xg = xin + row0 * 256;
#pragma unroll
    for (int rep = 0; rep < 32; ++rep) {
      int i = rep * 256 + tid;               // float4 index in tile
      int r = i >> 6, c4 = (i & 63) << 2;
      float4 v = *(const float4*)(xg + r * 256 + c4);
      union { __bf16 h[4]; unsigned long long u; } p;
      p.h[0] = (__bf16)v.x; p.h[1] = (__bf16)v.y;
      p.h[2] = (__bf16)v.z; p.h[3] = (__bf16)v.w;
      int byte = r * 512 + ((c4 * 2) ^ ((r & 7) << 4));
      *(unsigned long long*)(act + byte) = p.u;
    }
  } else {
    const BF16* og = oin + row0 * 256;
#pragma unroll
    for (int rep = 0; rep < 16; ++rep) {
      int i = rep * 256 + tid;               // 16B granule index
      int r = i >> 5, g = i & 31;
      uint4 v = *(const uint4*)(og + r * 256 + g * 8);
      int byte = r * 512 + ((g * 16) ^ ((r & 7) << 4));
      *(uint4*)(act + byte) = v;
    }
  }
  __syncthreads();

  const int NL = (VARIANT == 0) ? 5 : (VARIANT == 1 ? 4 : 1);
#pragma unroll 1
  for (int L = 0; L < NL; ++L) {
    const BF16* wp = args.w[L] + (size_t)(wc * 128 + fr) * 256 + fq * 8;
    f32x4 acc[4][8];
#pragma unroll
    for (int nr = 0; nr < 4; ++nr)
#pragma unroll
      for (int nc = 0; nc < 8; ++nc)
#pragma unroll
        for (int j = 0; j < 4; ++j) acc[nr][nc][j] = 0.f;

    // K-loop: weights from L2 -> regs, act from swizzled LDS. No barriers inside.
#pragma unroll
    for (int kt = 0; kt < 8; ++kt) {
      bf16x8 bv[8], af[4];
#pragma unroll
      for (int nc = 0; nc < 8; ++nc)
        bv[nc] = *(const bf16x8*)(wp + nc * 16 * 256 + kt * 32);
#pragma unroll
      for (int nr = 0; nr < 4; ++nr) {
        int r = wr * 64 + nr * 16 + fr;
        int byte = r * 512 + ((kt * 64 + fq * 16) ^ ((r & 7) << 4));
        af[nr] = *(const bf16x8*)(act + byte);
      }
#pragma unroll
      for (int nr = 0; nr < 4; ++nr)
#pragma unroll
        for (int nc = 0; nc < 8; ++nc)
          acc[nr][nc] = __builtin_amdgcn_mfma_f32_16x16x32_bf16(bv[nc], af[nr], acc[nr][nc], 0, 0, 0);
    }
    __syncthreads();   // all act reads done before any epilogue write

    if (VARIANT == 0 && L == 4) {
      // mixed epilogue: f32 global + per-column (over 128 rows) max/sumexp partials
      float* mg = fout + (row0 + wr * 64) * 256 + wc * 128;
#pragma unroll
      for (int nc = 0; nc < 8; ++nc) {
#pragma unroll
        for (int nr = 0; nr < 4; ++nr) {
          float4 st = { acc[nr][nc][0], acc[nr][nc][1], acc[nr][nc][2], acc[nr][nc][3] };
          *(float4*)(mg + (size_t)(nr * 16 + fr) * 256 + nc * 16 + fq * 4) = st;
        }
        float mx[4], sm[4];
#pragma unroll
        for (int jj = 0; jj < 4; ++jj) {
          float m0 = fmaxf(fmaxf(acc[0][nc][jj], acc[1][nc][jj]),
                           fmaxf(acc[2][nc][jj], acc[3][nc][jj]));
#pragma unroll
          for (int d = 1; d < 16; d <<= 1) m0 = fmaxf(m0, __shfl_xor(m0, d));
          float s0 = 0.f;
#pragma unroll
          for (int nr = 0; nr < 4; ++nr) s0 += __expf(acc[nr][nc][jj] - m0);
#pragma unroll
          for (int d = 1; d < 16; d <<= 1) s0 += __shfl_xor(s0, d);
          mx[jj] = m0; sm[jj] = s0;
        }
        if (fr == 0) {
          int pb = blk * 2 + wr;
          int col = wc * 128 + nc * 16 + fq * 4;
          *(float4*)(pm + (size_t)pb * 256 + col) = {mx[0], mx[1], mx[2], mx[3]};
          *(float4*)(ps + (size_t)pb * 256 + col) = {sm[0], sm[1], sm[2], sm[3]};
        }
      }
    } else if (VARIANT == 2) {
      float* og = fout + (row0 + wr * 64) * 256 + wc * 128;
#pragma unroll
      for (int nc = 0; nc < 8; ++nc) {
        float4 b4 = *(const float4*)(args.b[0] + wc * 128 + nc * 16 + fq * 4);
#pragma unroll
        for (int nr = 0; nr < 4; ++nr) {
          float4 st = { acc[nr][nc][0] + b4.x, acc[nr][nc][1] + b4.y,
                        acc[nr][nc][2] + b4.z, acc[nr][nc][3] + b4.w };
          *(float4*)(og + (size_t)(nr * 16 + fr) * 256 + nc * 16 + fq * 4) = st;
        }
      }
    } else {
      // MLP layer epilogue: bias (+gelu for L<3) + residual; write LDS (or v to global)
      const float* bb = args.b[L];
#pragma unroll
      for (int nc = 0; nc < 8; ++nc) {
        float4 b4 = *(const float4*)(bb + wc * 128 + nc * 16 + fq * 4);
#pragma unroll
        for (int nr = 0; nr < 4; ++nr) {
          int r = wr * 64 + nr * 16 + fr;
          int cb2 = wc * 256 + nc * 32 + fq * 8;
          int byte = r * 512 + (cb2 ^ ((r & 7) << 4));
          union { __bf16 h[4]; unsigned long long u; } res, w2;
          res.u = *(unsigned long long*)(act + byte);
          float o0 = acc[nr][nc][0] + b4.x;
          float o1 = acc[nr][nc][1] + b4.y;
          float o2 = acc[nr][nc][2] + b4.z;
          float o3 = acc[nr][nc][3] + b4.w;
          if (L < 3) { o0 = gelu_erf(o0); o1 = gelu_erf(o1);
                       o2 = gelu_erf(o2); o3 = gelu_erf(o3); }
          w2.h[0] = (__bf16)((float)res.h[0] + o0);
          w2.h[1] = (__bf16)((float)res.h[1] + o1);
          w2.h[2] = (__bf16)((float)res.h[2] + o2);
          w2.h[3] = (__bf16)((float)res.h[3] + o3);
          if (VARIANT == 1 && L == 3) {
            *(unsigned long long*)((char*)bout + ((row0 + r) * 512 + cb2)) = w2.u;
          } else {
            *(unsigned long long*)(act + byte) = w2.u;
          }
        }
      }
      if (L != NL - 1) __syncthreads();
    }
  }
}

// ---------------- softmax-over-N merge ----------------
__global__ void softmax_merge(const float* __restrict__ pm, const float* __restrict__ ps,
                              float* __restrict__ Mf, float* __restrict__ Sf) {
  int b = blockIdx.x, t = threadIdx.x;
  const float* pmb = pm + (size_t)b * 512 * 256;
  const float* psb = ps + (size_t)b * 512 * 256;
  float m = -3.0e38f, s = 0.f;
  for (int c = 0; c < 512; ++c) {
    float m2 = pmb[c * 256 + t];
    float s2 = psb[c * 256 + t];
    float mn = fmaxf(m, m2);
    s = s * __expf(m - mn) + s2 * __expf(m2 - mn);
    m = mn;
  }
  Mf[b * 256 + t] = m;
  Sf[b * 256 + t] = 1.f / s;
}

// ---------------- z = enc @ v (partials over n-chunks) ----------------
__global__ __launch_bounds__(256) void z_partial_mfma(
    const float* __restrict__ mixed, const BF16* __restrict__ v,
    const float* __restrict__ Mf, float* __restrict__ zpart) {
  int ci = blockIdx.x;                 // B*64 blocks, 512 rows each
  int b = ci >> 6, ch = ci & 63;
  int tid = threadIdx.x, wid = tid >> 6, lane = tid & 63;
  int l31 = lane & 31, kh = lane >> 5;
  size_t n0 = (size_t)b * 32768 + ch * 512;
  for (int hi = 0; hi < 2; ++hi) {
    int h = wid * 2 + hi;
    int col = h * 32 + l31;
    float Mp = Mf[b * 256 + col];
    f32x16 acc;
#pragma unroll
    for (int r = 0; r < 16; ++r) acc[r] = 0.f;
    for (int s = 0; s < 32; ++s) {
      bf16x8 ea, vb;
      size_t nbase = n0 + s * 16 + kh * 8;
#pragma unroll
      for (int j = 0; j < 8; ++j) {
        float x = __expf(mixed[(nbase + j) * 256 + col] - Mp);
        ea[j] = (__bf16)x;
        vb[j] = *(const __bf16*)&v[(nbase + j) * 256 + col];
      }
      acc = __builtin_amdgcn_mfma_f32_32x32x16_bf16(ea, vb, acc, 0, 0, 0);
    }
    float* zp = zpart + (size_t)ci * 8192 + h * 1024;
#pragma unroll
    for (int reg = 0; reg < 16; ++reg) {
      int m = (reg & 3) + 8 * (reg >> 2) + 4 * kh;
      zp[m * 32 + l31] = acc[reg];
    }
  }
}

__global__ void z_merge(const float* __restrict__ zpart, const float* __restrict__ Sf,
                        float* __restrict__ z) {
  int i = blockIdx.x * 256 + threadIdx.x;   // [0, 4*8192)
  int b = i >> 13, j = i & 8191;
  int p = j >> 5;                           // h*32 + m
  float s = 0.f;
  for (int c = 0; c < 64; ++c) s += zpart[(size_t)(b * 64 + c) * 8192 + j];
  z[i] = s * Sf[b * 256 + p];
}

// ---------------- o = dec^T @ z ----------------
__global__ __launch_bounds__(256) void decode_o_mfma(
    const float* __restrict__ mixed, const float* __restrict__ z,
    BF16* __restrict__ o) {
  int ci = blockIdx.x;
  int b = ci >> 6, ch = ci & 63;
  int tid = threadIdx.x, wid = tid >> 6, lane = tid & 63;
  int l31 = lane & 31, kh = lane >> 5;
  size_t rowbase = (size_t)b * 32768 + ch * 512;
  for (int hi = 0; hi < 2; ++hi) {
    int h = wid * 2 + hi;
    bf16x8 zf[2];
#pragma unroll
    for (int ks = 0; ks < 2; ++ks)
#pragma unroll
      for (int j = 0; j < 8; ++j)
        zf[ks][j] = (__bf16)z[b * 8192 + h * 1024 + (ks * 16 + kh * 8 + j) * 32 + l31];
    for (int s = 0; s < 16; ++s) {
      size_t n = rowbase + s * 32 + l31;
      const float* mrow = mixed + n * 256 + h * 32;
      float xv[16];
#pragma unroll
      for (int ks = 0; ks < 2; ++ks) {
        float4 a  = *(const float4*)(mrow + ks * 16 + kh * 8);
        float4 c4 = *(const float4*)(mrow + ks * 16 + kh * 8 + 4);
        xv[ks * 8 + 0] = a.x;  xv[ks * 8 + 1] = a.y;  xv[ks * 8 + 2] = a.z;  xv[ks * 8 + 3] = a.w;
        xv[ks * 8 + 4] = c4.x; xv[ks * 8 + 5] = c4.y; xv[ks * 8 + 6] = c4.z; xv[ks * 8 + 7] = c4.w;
      }
      float mx = xv[0];
#pragma unroll
      for (int i = 1; i < 16; ++i) mx = fmaxf(mx, xv[i]);
      mx = fmaxf(mx, __shfl_xor(mx, 32));
      float sm = 0.f, ev[16];
#pragma unroll
      for (int i = 0; i < 16; ++i) { ev[i] = __expf(xv[i] - mx); sm += ev[i]; }
      sm += __shfl_xor(sm, 32);
      float inv = 1.f / sm;
      bf16x8 af[2];
#pragma unroll
      for (int ks = 0; ks < 2; ++ks)
#pragma unroll
        for (int j = 0; j < 8; ++j) af[ks][j] = (__bf16)(ev[ks * 8 + j] * inv);
      f32x16 acc;
#pragma unroll
      for (int r = 0; r < 16; ++r) acc[r] = 0.f;
      acc = __builtin_amdgcn_mfma_f32_32x32x16_bf16(af[0], zf[0], acc, 0, 0, 0);
      acc = __builtin_amdgcn_mfma_f32_32x32x16_bf16(af[1], zf[1], acc, 0, 0, 0);
#pragma unroll
      for (int reg = 0; reg < 16; ++reg) {
        int nr = (reg & 3) + 8 * (reg >> 2) + 4 * kh;
        o[(rowbase + s * 32 + nr) * 256 + h * 32 + l31] = __float2bfloat16(acc[reg]);
      }
    }
  }
}

// ---------------- launch ----------------
extern "C" void kernel_launch(void* const* d_in, const int* in_sizes, int n_in,
                              void* d_out, int out_size, void* d_ws, size_t ws_size,
                              hipStream_t stream) {
  const float* x     = (const float*)d_in[0];
  const float* lq    = (const float*)d_in[1];
  const float* kfc1b = (const float*)d_in[3];
  const float* kfcsb = (const float*)d_in[5];
  const float* kfc2b = (const float*)d_in[7];
  const float* vfc1b = (const float*)d_in[9];
  const float* vfcsb = (const float*)d_in[11];
  const float* vfc2b = (const float*)d_in[13];
  const float* mixw  = (const float*)d_in[14];
  const float* outb  = (const float*)d_in[16];

  const int R = in_sizes[0] / 256;          // 131072 rows (B*N)

  char* ws = (char*)d_ws;
  BF16*  v     = (BF16*)(ws);                    // 67,108,864 B
  BF16*  o     = (BF16*)(ws + 67108864);         // 67,108,864 B
  BF16*  wbf   = (BF16*)(ws + 134217728);        //  1,179,648 B
  BF16*  wt    = (BF16*)(ws + 135397376);        //    131,072 B
  float* pm    = (float*)(ws + 135528448);       //  2,097,152 B
  float* ps    = (float*)(ws + 137625600);       //  2,097,152 B
  float* Mf    = (float*)(ws + 139722752);       //      4,096 B
  float* Sf    = (float*)(ws + 139726848);       //      4,096 B
  float* zpart = (float*)(ws + 139730944);       //  8,388,608 B
  float* z     = (float*)(ws + 148119552);       //    131,072 B
  float* mixed = (float*)d_out;                  // d_out doubles as mixed (f32)

  // prep
  WPtrs wp = {{(const float*)d_in[2], (const float*)d_in[4], (const float*)d_in[4] + 65536,
               (const float*)d_in[6], (const float*)d_in[8], (const float*)d_in[10],
               (const float*)d_in[10] + 65536, (const float*)d_in[12], (const float*)d_in[15]}};
  cast_w_kernel<<<2304, 256, 0, stream>>>(wp, wbf);
  build_wtilde<<<256, 256, 0, stream>>>(mixw, lq, wt);

  const int G = R / 128;   // 1024

  // F1: k-MLP + mixed + stats
  FArgs a1;
  a1.w[0] = wbf + 0;      a1.b[0] = kfc1b;
  a1.w[1] = wbf + 65536;  a1.b[1] = kfcsb;
  a1.w[2] = wbf + 131072; a1.b[2] = kfcsb + 256;
  a1.w[3] = wbf + 196608; a1.b[3] = kfc2b;
  a1.w[4] = wt;           a1.b[4] = nullptr;
  fused_mlp<0><<<G, 256, 0, stream>>>(x, nullptr, a1, mixed, nullptr, pm, ps);

  // F2: v-MLP
  FArgs a2;
  a2.w[0] = wbf + 262144; a2.b[0] = vfc1b;
  a2.w[1] = wbf + 327680; a2.b[1] = vfcsb;
  a2.w[2] = wbf + 393216; a2.b[2] = vfcsb + 256;
  a2.w[3] = wbf + 458752; a2.b[3] = vfc2b;
  a2.w[4] = nullptr;      a2.b[4] = nullptr;
  fused_mlp<1><<<G, 256, 0, stream>>>(x, nullptr, a2, nullptr, v, nullptr, nullptr);

  // softmax-over-N merge
  softmax_merge<<<4, 256, 0, stream>>>(pm, ps, Mf, Sf);

  // z = enc @ v
  z_partial_mfma<<<256, 256, 0, stream>>>(mixed, v, Mf, zpart);
  z_merge<<<128, 256, 0, stream>>>(zpart, Sf, z);

  // o = dec^T @ z
  decode_o_mfma<<<256, 256, 0, stream>>>(mixed, z, o);

  // final: out = o @ out_w^T + out_b  (f32 into d_out, overwrites mixed)
  FArgs a3;
  a3.w[0] = wbf + 524288; a3.b[0] = outb;
  for (int i = 1; i < 5; ++i) { a3.w[i] = nullptr; a3.b[i] = nullptr; }
  fused_mlp<2><<<G, 256, 0, stream>>>(nullptr, o, a3, (float*)d_out, nullptr, nullptr, nullptr);
}

// Round 3
// 673.142 us; speedup vs baseline: 1.4552x; 1.3329x over previous
//
#include <hip/hip_runtime.h>
#include <hip/hip_bf16.h>
#include <math.h>

#define BF16 __hip_bfloat16

typedef __bf16 bf16x8 __attribute__((ext_vector_type(8)));
typedef float  f32x4  __attribute__((ext_vector_type(4)));
typedef float  f32x16 __attribute__((ext_vector_type(16)));

__device__ inline float gelu_erf(float x) {
  return 0.5f * x * (1.0f + erff(x * 0.70710678118654752f));
}

struct WPtrs { const float* p[9]; };
struct FArgs { const BF16* w[5]; const float* b[5]; };

// ---------------- small prep kernels ----------------
__global__ void cast_w_kernel(WPtrs wp, BF16* __restrict__ out) {
  int i = blockIdx.x * 256 + threadIdx.x;   // < 9*65536
  int seg = i >> 16, off = i & 65535;
  out[i] = __float2bfloat16(wp.p[seg][off]);
}

// W~[p, h*32+d] = sum_j mix_w[p, h*32+j] * latent_q[h*32+j, d]
__global__ void build_wtilde(const float* __restrict__ mixw, const float* __restrict__ lq,
                             BF16* __restrict__ wt) {
  int p = blockIdx.x, c = threadIdx.x;
  int h = c >> 5, d = c & 31;
  float s = 0.f;
#pragma unroll
  for (int j = 0; j < 32; ++j)
    s += mixw[p * 256 + h * 32 + j] * lq[(h * 32 + j) * 32 + d];
  wt[p * 256 + c] = __float2bfloat16(s);
}

// ---------------- fused resident-tile MLP helpers ----------------
__device__ inline void loadw4(bf16x8 (&dst)[4], const BF16* wp, int kt) {
#pragma unroll
  for (int nc = 0; nc < 4; ++nc)
    dst[nc] = *(const bf16x8*)(wp + nc * 16 * 256 + kt * 32);
}

__device__ inline void loada4(bf16x8 (&dst)[4], const char* act, int kt, int fr, int fq) {
#pragma unroll
  for (int nr = 0; nr < 4; ++nr) {
    int r = nr * 16 + fr;
    dst[nr] = *(const bf16x8*)(act + r * 512 + ((kt * 64 + fq * 16) ^ ((r & 7) << 4)));
  }
}

__device__ inline void mfma16(f32x4 (&acc)[4][4], const bf16x8 (&bv)[4], const bf16x8 (&af)[4]) {
#pragma unroll
  for (int nr = 0; nr < 4; ++nr)
#pragma unroll
    for (int nc = 0; nc < 4; ++nc)
      acc[nr][nc] = __builtin_amdgcn_mfma_f32_16x16x32_bf16(bv[nc], af[nr], acc[nr][nc], 0, 0, 0);
}

// ---------------- fused resident-tile MLP ----------------
// VARIANT 0: k-MLP(4 layers) + mixed(=k@Wt^T, f32 out) + softmax-N partial stats
// VARIANT 1: v-MLP(4 layers) -> bf16 global
// VARIANT 2: final projection (1 layer, bias, f32 out)
// act tile: 64 rows x 256 cols bf16 (32KB), XOR-swizzled (byte ^= (r&7)<<4)
// 4 waves split 256 output cols (64 each); per-wave acc[4][4] (64 rows x 64 cols)
template <int VARIANT>
__global__ __launch_bounds__(256, 4) void fused_mlp(
    const float* __restrict__ xin, const BF16* __restrict__ oin, FArgs args,
    float* __restrict__ fout, BF16* __restrict__ bout,
    float* __restrict__ pm, float* __restrict__ ps) {
  __shared__ __align__(16) char act[64 * 512];
  const int tid = threadIdx.x;
  const int blk = blockIdx.x;
  const int wc = tid >> 6, lane = tid & 63;
  const int fr = lane & 15, fq = lane >> 4;
  const size_t row0 = (size_t)blk * 64;

  // ---- stage input tile into swizzled LDS ----
  if (VARIANT != 2) {
    const float* xg = xin + row0 * 256;
#pragma unroll
    for (int rep = 0; rep < 16; ++rep) {
      int i = rep * 256 + tid;               // float4 index in tile (4096 total)
      int r = i >> 6, c4 = (i & 63) << 2;
      float4 v = *(const float4*)(xg + r * 256 + c4);
      union { __bf16 h[4]; unsigned long long u; } p;
      p.h[0] = (__bf16)v.x; p.h[1] = (__bf16)v.y;
      p.h[2] = (__bf16)v.z; p.h[3] = (__bf16)v.w;
      int byte = r * 512 + ((c4 * 2) ^ ((r & 7) << 4));
      *(unsigned long long*)(act + byte) = p.u;
    }
  } else {
    const BF16* og = oin + row0 * 256;
#pragma unroll
    for (int rep = 0; rep < 8; ++rep) {
      int i = rep * 256 + tid;               // 16B granule index (2048 total)
      int r = i >> 5, g = i & 31;
      uint4 v = *(const uint4*)(og + r * 256 + g * 8);
      int byte = r * 512 + ((g * 16) ^ ((r & 7) << 4));
      *(uint4*)(act + byte) = v;
    }
  }
  __syncthreads();

  const int NL = (VARIANT == 0) ? 5 : (VARIANT == 1 ? 4 : 1);
#pragma unroll 1
  for (int L = 0; L < NL; ++L) {
    const BF16* wp = args.w[L] + (size_t)(wc * 64 + fr) * 256 + fq * 8;
    f32x4 acc[4][4];
#pragma unroll
    for (int nr = 0; nr < 4; ++nr)
#pragma unroll
      for (int nc = 0; nc < 4; ++nc)
#pragma unroll
        for (int j = 0; j < 4; ++j) acc[nr][nc][j] = 0.f;

    // K-loop: weights from L2 -> regs (2-stage double buffer), act from LDS.
    {
      bf16x8 bvA[4], bvB[4], af[4];
      loadw4(bvA, wp, 0);
#pragma unroll
      for (int kp = 0; kp < 4; ++kp) {
        loadw4(bvB, wp, 2 * kp + 1);
        loada4(af, act, 2 * kp, fr, fq);
        mfma16(acc, bvA, af);
        if (kp < 3) loadw4(bvA, wp, 2 * kp + 2);
        loada4(af, act, 2 * kp + 1, fr, fq);
        mfma16(acc, bvB, af);
      }
    }
    __syncthreads();   // all act reads done before any epilogue write

    if (VARIANT == 0 && L == 4) {
      // mixed epilogue: f32 global + per-column (over 64 rows) max/sumexp partials
      float* mg = fout + row0 * 256;
#pragma unroll
      for (int nc = 0; nc < 4; ++nc) {
#pragma unroll
        for (int nr = 0; nr < 4; ++nr) {
          float4 st = { acc[nr][nc][0], acc[nr][nc][1], acc[nr][nc][2], acc[nr][nc][3] };
          *(float4*)(mg + (size_t)(nr * 16 + fr) * 256 + wc * 64 + nc * 16 + fq * 4) = st;
        }
        float mx[4], sm[4];
#pragma unroll
        for (int jj = 0; jj < 4; ++jj) {
          float m0 = fmaxf(fmaxf(acc[0][nc][jj], acc[1][nc][jj]),
                           fmaxf(acc[2][nc][jj], acc[3][nc][jj]));
#pragma unroll
          for (int d = 1; d < 16; d <<= 1) m0 = fmaxf(m0, __shfl_xor(m0, d));
          float s0 = 0.f;
#pragma unroll
          for (int nr = 0; nr < 4; ++nr) s0 += __expf(acc[nr][nc][jj] - m0);
#pragma unroll
          for (int d = 1; d < 16; d <<= 1) s0 += __shfl_xor(s0, d);
          mx[jj] = m0; sm[jj] = s0;
        }
        if (fr == 0) {
          int col = wc * 64 + nc * 16 + fq * 4;
          *(float4*)(pm + (size_t)blk * 256 + col) = {mx[0], mx[1], mx[2], mx[3]};
          *(float4*)(ps + (size_t)blk * 256 + col) = {sm[0], sm[1], sm[2], sm[3]};
        }
      }
    } else if (VARIANT == 2) {
      float* og = fout + row0 * 256;
#pragma unroll
      for (int nc = 0; nc < 4; ++nc) {
        float4 b4 = *(const float4*)(args.b[0] + wc * 64 + nc * 16 + fq * 4);
#pragma unroll
        for (int nr = 0; nr < 4; ++nr) {
          float4 st = { acc[nr][nc][0] + b4.x, acc[nr][nc][1] + b4.y,
                        acc[nr][nc][2] + b4.z, acc[nr][nc][3] + b4.w };
          *(float4*)(og + (size_t)(nr * 16 + fr) * 256 + wc * 64 + nc * 16 + fq * 4) = st;
        }
      }
    } else {
      // MLP layer epilogue: bias (+gelu for L<3) + residual; write LDS (or v to global)
      const float* bb = args.b[L];
#pragma unroll
      for (int nc = 0; nc < 4; ++nc) {
        float4 b4 = *(const float4*)(bb + wc * 64 + nc * 16 + fq * 4);
#pragma unroll
        for (int nr = 0; nr < 4; ++nr) {
          int r = nr * 16 + fr;
          int cb2 = wc * 128 + nc * 32 + fq * 8;     // byte offset of 4 bf16 cols
          int byte = r * 512 + (cb2 ^ ((r & 7) << 4));
          union { __bf16 h[4]; unsigned long long u; } res, w2;
          res.u = *(unsigned long long*)(act + byte);
          float o0 = acc[nr][nc][0] + b4.x;
          float o1 = acc[nr][nc][1] + b4.y;
          float o2 = acc[nr][nc][2] + b4.z;
          float o3 = acc[nr][nc][3] + b4.w;
          if (L < 3) { o0 = gelu_erf(o0); o1 = gelu_erf(o1);
                       o2 = gelu_erf(o2); o3 = gelu_erf(o3); }
          w2.h[0] = (__bf16)((float)res.h[0] + o0);
          w2.h[1] = (__bf16)((float)res.h[1] + o1);
          w2.h[2] = (__bf16)((float)res.h[2] + o2);
          w2.h[3] = (__bf16)((float)res.h[3] + o3);
          if (VARIANT == 1 && L == 3) {
            *(unsigned long long*)((char*)bout + ((row0 + r) * 512 + cb2)) = w2.u;
          } else {
            *(unsigned long long*)(act + byte) = w2.u;
          }
        }
      }
      if (L != NL - 1) __syncthreads();
    }
  }
}

// ---------------- softmax-over-N merge ----------------
__global__ void softmax_merge(const float* __restrict__ pm, const float* __restrict__ ps,
                              float* __restrict__ Mf, float* __restrict__ Sf) {
  int b = blockIdx.x, t = threadIdx.x;
  const float* pmb = pm + (size_t)b * 512 * 256;
  const float* psb = ps + (size_t)b * 512 * 256;
  float m = -3.0e38f, s = 0.f;
  for (int c = 0; c < 512; ++c) {
    float m2 = pmb[c * 256 + t];
    float s2 = psb[c * 256 + t];
    float mn = fmaxf(m, m2);
    s = s * __expf(m - mn) + s2 * __expf(m2 - mn);
    m = mn;
  }
  Mf[b * 256 + t] = m;
  Sf[b * 256 + t] = 1.f / s;
}

// ---------------- z = enc @ v (partials over n-chunks) ----------------
__global__ __launch_bounds__(256) void z_partial_mfma(
    const float* __restrict__ mixed, const BF16* __restrict__ v,
    const float* __restrict__ Mf, float* __restrict__ zpart) {
  int ci = blockIdx.x;                 // B*64 blocks, 512 rows each
  int b = ci >> 6, ch = ci & 63;
  int tid = threadIdx.x, wid = tid >> 6, lane = tid & 63;
  int l31 = lane & 31, kh = lane >> 5;
  size_t n0 = (size_t)b * 32768 + ch * 512;
  for (int hi = 0; hi < 2; ++hi) {
    int h = wid * 2 + hi;
    int col = h * 32 + l31;
    float Mp = Mf[b * 256 + col];
    f32x16 acc;
#pragma unroll
    for (int r = 0; r < 16; ++r) acc[r] = 0.f;
    for (int s = 0; s < 32; ++s) {
      bf16x8 ea, vb;
      size_t nbase = n0 + s * 16 + kh * 8;
#pragma unroll
      for (int j = 0; j < 8; ++j) {
        float x = __expf(mixed[(nbase + j) * 256 + col] - Mp);
        ea[j] = (__bf16)x;
        vb[j] = *(const __bf16*)&v[(nbase + j) * 256 + col];
      }
      acc = __builtin_amdgcn_mfma_f32_32x32x16_bf16(ea, vb, acc, 0, 0, 0);
    }
    float* zp = zpart + (size_t)ci * 8192 + h * 1024;
#pragma unroll
    for (int reg = 0; reg < 16; ++reg) {
      int m = (reg & 3) + 8 * (reg >> 2) + 4 * kh;
      zp[m * 32 + l31] = acc[reg];
    }
  }
}

__global__ void z_merge(const float* __restrict__ zpart, const float* __restrict__ Sf,
                        float* __restrict__ z) {
  int i = blockIdx.x * 256 + threadIdx.x;   // [0, 4*8192)
  int b = i >> 13, j = i & 8191;
  int p = j >> 5;                           // h*32 + m
  float s = 0.f;
  for (int c = 0; c < 64; ++c) s += zpart[(size_t)(b * 64 + c) * 8192 + j];
  z[i] = s * Sf[b * 256 + p];
}

// ---------------- o = dec^T @ z ----------------
__global__ __launch_bounds__(256) void decode_o_mfma(
    const float* __restrict__ mixed, const float* __restrict__ z,
    BF16* __restrict__ o) {
  int ci = blockIdx.x;
  int b = ci >> 6, ch = ci & 63;
  int tid = threadIdx.x, wid = tid >> 6, lane = tid & 63;
  int l31 = lane & 31, kh = lane >> 5;
  size_t rowbase = (size_t)b * 32768 + ch * 512;
  for (int hi = 0; hi < 2; ++hi) {
    int h = wid * 2 + hi;
    bf16x8 zf[2];
#pragma unroll
    for (int ks = 0; ks < 2; ++ks)
#pragma unroll
      for (int j = 0; j < 8; ++j)
        zf[ks][j] = (__bf16)z[b * 8192 + h * 1024 + (ks * 16 + kh * 8 + j) * 32 + l31];
    for (int s = 0; s < 16; ++s) {
      size_t n = rowbase + s * 32 + l31;
      const float* mrow = mixed + n * 256 + h * 32;
      float xv[16];
#pragma unroll
      for (int ks = 0; ks < 2; ++ks) {
        float4 a  = *(const float4*)(mrow + ks * 16 + kh * 8);
        float4 c4 = *(const float4*)(mrow + ks * 16 + kh * 8 + 4);
        xv[ks * 8 + 0] = a.x;  xv[ks * 8 + 1] = a.y;  xv[ks * 8 + 2] = a.z;  xv[ks * 8 + 3] = a.w;
        xv[ks * 8 + 4] = c4.x; xv[ks * 8 + 5] = c4.y; xv[ks * 8 + 6] = c4.z; xv[ks * 8 + 7] = c4.w;
      }
      float mx = xv[0];
#pragma unroll
      for (int i = 1; i < 16; ++i) mx = fmaxf(mx, xv[i]);
      mx = fmaxf(mx, __shfl_xor(mx, 32));
      float sm = 0.f, ev[16];
#pragma unroll
      for (int i = 0; i < 16; ++i) { ev[i] = __expf(xv[i] - mx); sm += ev[i]; }
      sm += __shfl_xor(sm, 32);
      float inv = 1.f / sm;
      bf16x8 af[2];
#pragma unroll
      for (int ks = 0; ks < 2; ++ks)
#pragma unroll
        for (int j = 0; j < 8; ++j) af[ks][j] = (__bf16)(ev[ks * 8 + j] * inv);
      f32x16 acc;
#pragma unroll
      for (int r = 0; r < 16; ++r) acc[r] = 0.f;
      acc = __builtin_amdgcn_mfma_f32_32x32x16_bf16(af[0], zf[0], acc, 0, 0, 0);
      acc = __builtin_amdgcn_mfma_f32_32x32x16_bf16(af[1], zf[1], acc, 0, 0, 0);
#pragma unroll
      for (int reg = 0; reg < 16; ++reg) {
        int nr = (reg & 3) + 8 * (reg >> 2) + 4 * kh;
        o[(rowbase + s * 32 + nr) * 256 + h * 32 + l31] = __float2bfloat16(acc[reg]);
      }
    }
  }
}

// ---------------- launch ----------------
extern "C" void kernel_launch(void* const* d_in, const int* in_sizes, int n_in,
                              void* d_out, int out_size, void* d_ws, size_t ws_size,
                              hipStream_t stream) {
  const float* x     = (const float*)d_in[0];
  const float* lq    = (const float*)d_in[1];
  const float* kfc1b = (const float*)d_in[3];
  const float* kfcsb = (const float*)d_in[5];
  const float* kfc2b = (const float*)d_in[7];
  const float* vfc1b = (const float*)d_in[9];
  const float* vfcsb = (const float*)d_in[11];
  const float* vfc2b = (const float*)d_in[13];
  const float* mixw  = (const float*)d_in[14];
  const float* outb  = (const float*)d_in[16];

  const int R = in_sizes[0] / 256;          // 131072 rows (B*N)

  char* ws = (char*)d_ws;
  BF16*  v     = (BF16*)(ws);                    // 67,108,864 B
  BF16*  o     = (BF16*)(ws + 67108864);         // 67,108,864 B
  BF16*  wbf   = (BF16*)(ws + 134217728);        //  1,179,648 B
  BF16*  wt    = (BF16*)(ws + 135397376);        //    131,072 B
  float* pm    = (float*)(ws + 135528448);       //  2,097,152 B
  float* ps    = (float*)(ws + 137625600);       //  2,097,152 B
  float* Mf    = (float*)(ws + 139722752);       //      4,096 B
  float* Sf    = (float*)(ws + 139726848);       //      4,096 B
  float* zpart = (float*)(ws + 139730944);       //  8,388,608 B
  float* z     = (float*)(ws + 148119552);       //    131,072 B
  float* mixed = (float*)d_out;                  // d_out doubles as mixed (f32)

  // prep
  WPtrs wp = {{(const float*)d_in[2], (const float*)d_in[4], (const float*)d_in[4] + 65536,
               (const float*)d_in[6], (const float*)d_in[8], (const float*)d_in[10],
               (const float*)d_in[10] + 65536, (const float*)d_in[12], (const float*)d_in[15]}};
  cast_w_kernel<<<2304, 256, 0, stream>>>(wp, wbf);
  build_wtilde<<<256, 256, 0, stream>>>(mixw, lq, wt);

  const int G = R / 64;   // 2048

  // F1: k-MLP + mixed + stats
  FArgs a1;
  a1.w[0] = wbf + 0;      a1.b[0] = kfc1b;
  a1.w[1] = wbf + 65536;  a1.b[1] = kfcsb;
  a1.w[2] = wbf + 131072; a1.b[2] = kfcsb + 256;
  a1.w[3] = wbf + 196608; a1.b[3] = kfc2b;
  a1.w[4] = wt;           a1.b[4] = nullptr;
  fused_mlp<0><<<G, 256, 0, stream>>>(x, nullptr, a1, mixed, nullptr, pm, ps);

  // F2: v-MLP
  FArgs a2;
  a2.w[0] = wbf + 262144; a2.b[0] = vfc1b;
  a2.w[1] = wbf + 327680; a2.b[1] = vfcsb;
  a2.w[2] = wbf + 393216; a2.b[2] = vfcsb + 256;
  a2.w[3] = wbf + 458752; a2.b[3] = vfc2b;
  a2.w[4] = nullptr;      a2.b[4] = nullptr;
  fused_mlp<1><<<G, 256, 0, stream>>>(x, nullptr, a2, nullptr, v, nullptr, nullptr);

  // softmax-over-N merge
  softmax_merge<<<4, 256, 0, stream>>>(pm, ps, Mf, Sf);

  // z = enc @ v
  z_partial_mfma<<<256, 256, 0, stream>>>(mixed, v, Mf, zpart);
  z_merge<<<128, 256, 0, stream>>>(zpart, Sf, z);

  // o = dec^T @ z
  decode_o_mfma<<<256, 256, 0, stream>>>(mixed, z, o);

  // final: out = o @ out_w^T + out_b  (f32 into d_out, overwrites mixed)
  FArgs a3;
  a3.w[0] = wbf + 524288; a3.b[0] = outb;
  for (int i = 1; i < 5; ++i) { a3.w[i] = nullptr; a3.b[i] = nullptr; }
  fused_mlp<2><<<G, 256, 0, stream>>>(nullptr, o, a3, (float*)d_out, nullptr, nullptr, nullptr);
}

// Round 4
// 586.918 us; speedup vs baseline: 1.6690x; 1.1469x over previous
//
#include <hip/hip_runtime.h>
#include <hip/hip_bf16.h>
#include <math.h>

#define BF16 __hip_bfloat16

typedef __bf16 bf16x8 __attribute__((ext_vector_type(8)));
typedef float  f32x4  __attribute__((ext_vector_type(4)));
typedef float  f32x16 __attribute__((ext_vector_type(16)));

// branch-free erf (Abramowitz-Stegun 7.1.26, |err| < 1.5e-7)
__device__ inline float gelu_erf(float x) {
  float xs = x * 0.70710678118654752f;
  float a = fabsf(xs);
  float t = __builtin_amdgcn_rcpf(1.0f + 0.3275911f * a);
  float p = 1.061405429f;
  p = p * t - 1.453152027f;
  p = p * t + 1.421413741f;
  p = p * t - 0.284496736f;
  p = p * t + 0.254829592f;
  float e = __expf(-a * a);
  float y = 1.0f - p * t * e;            // erf(|xs|)
  float s = copysignf(y, xs);            // erf(xs)
  return 0.5f * x * (1.0f + s);
}

struct WPtrs { const float* p[9]; };
struct FArgs { const BF16* w[5]; const float* b[5]; };

// ---------------- small prep kernels ----------------
__global__ void cast_w_kernel(WPtrs wp, BF16* __restrict__ out) {
  int i = blockIdx.x * 256 + threadIdx.x;   // < 9*65536
  int seg = i >> 16, off = i & 65535;
  out[i] = __float2bfloat16(wp.p[seg][off]);
}

// W~[p, h*32+d] = sum_j mix_w[p, h*32+j] * latent_q[h*32+j, d]
__global__ void build_wtilde(const float* __restrict__ mixw, const float* __restrict__ lq,
                             BF16* __restrict__ wt) {
  int p = blockIdx.x, c = threadIdx.x;
  int h = c >> 5, d = c & 31;
  float s = 0.f;
#pragma unroll
  for (int j = 0; j < 32; ++j)
    s += mixw[p * 256 + h * 32 + j] * lq[(h * 32 + j) * 32 + d];
  wt[p * 256 + c] = __float2bfloat16(s);
}

// ---------------- fused resident-tile MLP helpers ----------------
__device__ inline void loadw4(bf16x8 (&dst)[4], const BF16* wp, int kt) {
#pragma unroll
  for (int nc = 0; nc < 4; ++nc)
    dst[nc] = *(const bf16x8*)(wp + nc * 16 * 256 + kt * 32);
}

__device__ inline void loada4(bf16x8 (&dst)[4], const char* act, int kt, int fr, int fq) {
#pragma unroll
  for (int nr = 0; nr < 4; ++nr) {
    int r = nr * 16 + fr;
    dst[nr] = *(const bf16x8*)(act + r * 512 + ((kt * 64 + fq * 16) ^ ((r & 7) << 4)));
  }
}

__device__ inline void mfma16(f32x4 (&acc)[4][4], const bf16x8 (&bv)[4], const bf16x8 (&af)[4]) {
#pragma unroll
  for (int nr = 0; nr < 4; ++nr)
#pragma unroll
    for (int nc = 0; nc < 4; ++nc)
      acc[nr][nc] = __builtin_amdgcn_mfma_f32_16x16x32_bf16(bv[nc], af[nr], acc[nr][nc], 0, 0, 0);
}

// ---------------- fused resident-tile MLP ----------------
// VARIANT 0: k-MLP(4 layers) + mixed(=k@Wt^T, f32 out) + softmax-N partial stats
// VARIANT 1: v-MLP(4 layers) -> bf16 global
// VARIANT 2: final projection (1 layer, bias, f32 out)
// act tile: 64 rows x 256 cols bf16 (32KB), XOR-swizzled (byte ^= (r&7)<<4)
// 4 waves split 256 output cols (64 each); per-wave acc[4][4] (64 rows x 64 cols)
// K-loop: FULL 2-deep double-buffer of both weight (L2) and act (LDS) fragments.
// __launch_bounds__(256,3): VGPR cap ~168 so the compiler keeps the prefetch
// (at cap 128 it sank loads to just before use -> serial latency per kt).
template <int VARIANT>
__global__ __launch_bounds__(256, 3) void fused_mlp(
    const float* __restrict__ xin, const BF16* __restrict__ oin, FArgs args,
    float* __restrict__ fout, BF16* __restrict__ bout,
    float* __restrict__ pm, float* __restrict__ ps) {
  __shared__ __align__(16) char act[64 * 512];
  const int tid = threadIdx.x;
  const int blk = blockIdx.x;
  const int wc = tid >> 6, lane = tid & 63;
  const int fr = lane & 15, fq = lane >> 4;
  const size_t row0 = (size_t)blk * 64;

  // ---- stage input tile into swizzled LDS ----
  if (VARIANT != 2) {
    const float* xg = xin + row0 * 256;
#pragma unroll
    for (int rep = 0; rep < 16; ++rep) {
      int i = rep * 256 + tid;               // float4 index in tile (4096 total)
      int r = i >> 6, c4 = (i & 63) << 2;
      float4 v = *(const float4*)(xg + r * 256 + c4);
      union { __bf16 h[4]; unsigned long long u; } p;
      p.h[0] = (__bf16)v.x; p.h[1] = (__bf16)v.y;
      p.h[2] = (__bf16)v.z; p.h[3] = (__bf16)v.w;
      int byte = r * 512 + ((c4 * 2) ^ ((r & 7) << 4));
      *(unsigned long long*)(act + byte) = p.u;
    }
  } else {
    const BF16* og = oin + row0 * 256;
#pragma unroll
    for (int rep = 0; rep < 8; ++rep) {
      int i = rep * 256 + tid;               // 16B granule index (2048 total)
      int r = i >> 5, g = i & 31;
      uint4 v = *(const uint4*)(og + r * 256 + g * 8);
      int byte = r * 512 + ((g * 16) ^ ((r & 7) << 4));
      *(uint4*)(act + byte) = v;
    }
  }
  __syncthreads();

  const int NL = (VARIANT == 0) ? 5 : (VARIANT == 1 ? 4 : 1);
#pragma unroll 1
  for (int L = 0; L < NL; ++L) {
    const BF16* wp = args.w[L] + (size_t)(wc * 64 + fr) * 256 + fq * 8;
    f32x4 acc[4][4];
#pragma unroll
    for (int nr = 0; nr < 4; ++nr)
#pragma unroll
      for (int nc = 0; nc < 4; ++nc)
#pragma unroll
        for (int j = 0; j < 4; ++j) acc[nr][nc][j] = 0.f;

    // K-loop: 2-deep pipelined, weights from L2 -> regs, act from swizzled LDS.
    {
      bf16x8 bvA[4], bvB[4], afA[4], afB[4];
      loadw4(bvA, wp, 0);
      loada4(afA, act, 0, fr, fq);
#pragma unroll
      for (int kp = 0; kp < 4; ++kp) {
        loadw4(bvB, wp, 2 * kp + 1);
        loada4(afB, act, 2 * kp + 1, fr, fq);
        mfma16(acc, bvA, afA);
        if (kp < 3) {
          loadw4(bvA, wp, 2 * kp + 2);
          loada4(afA, act, 2 * kp + 2, fr, fq);
        }
        mfma16(acc, bvB, afB);
      }
    }
    __syncthreads();   // all act reads done before any epilogue write

    if (VARIANT == 0 && L == 4) {
      // mixed epilogue: f32 global + per-column (over 64 rows) max/sumexp partials
      float* mg = fout + row0 * 256;
#pragma unroll
      for (int nc = 0; nc < 4; ++nc) {
#pragma unroll
        for (int nr = 0; nr < 4; ++nr) {
          float4 st = { acc[nr][nc][0], acc[nr][nc][1], acc[nr][nc][2], acc[nr][nc][3] };
          *(float4*)(mg + (size_t)(nr * 16 + fr) * 256 + wc * 64 + nc * 16 + fq * 4) = st;
        }
        float mx[4], sm[4];
#pragma unroll
        for (int jj = 0; jj < 4; ++jj) {
          float m0 = fmaxf(fmaxf(acc[0][nc][jj], acc[1][nc][jj]),
                           fmaxf(acc[2][nc][jj], acc[3][nc][jj]));
#pragma unroll
          for (int d = 1; d < 16; d <<= 1) m0 = fmaxf(m0, __shfl_xor(m0, d));
          float s0 = 0.f;
#pragma unroll
          for (int nr = 0; nr < 4; ++nr) s0 += __expf(acc[nr][nc][jj] - m0);
#pragma unroll
          for (int d = 1; d < 16; d <<= 1) s0 += __shfl_xor(s0, d);
          mx[jj] = m0; sm[jj] = s0;
        }
        if (fr == 0) {
          int col = wc * 64 + nc * 16 + fq * 4;
          *(float4*)(pm + (size_t)blk * 256 + col) = {mx[0], mx[1], mx[2], mx[3]};
          *(float4*)(ps + (size_t)blk * 256 + col) = {sm[0], sm[1], sm[2], sm[3]};
        }
      }
    } else if (VARIANT == 2) {
      float* og = fout + row0 * 256;
#pragma unroll
      for (int nc = 0; nc < 4; ++nc) {
        float4 b4 = *(const float4*)(args.b[0] + wc * 64 + nc * 16 + fq * 4);
#pragma unroll
        for (int nr = 0; nr < 4; ++nr) {
          float4 st = { acc[nr][nc][0] + b4.x, acc[nr][nc][1] + b4.y,
                        acc[nr][nc][2] + b4.z, acc[nr][nc][3] + b4.w };
          *(float4*)(og + (size_t)(nr * 16 + fr) * 256 + wc * 64 + nc * 16 + fq * 4) = st;
        }
      }
    } else {
      // MLP layer epilogue: bias (+gelu for L<3) + residual; write LDS (or v to global)
      const float* bb = args.b[L];
#pragma unroll
      for (int nc = 0; nc < 4; ++nc) {
        float4 b4 = *(const float4*)(bb + wc * 64 + nc * 16 + fq * 4);
#pragma unroll
        for (int nr = 0; nr < 4; ++nr) {
          int r = nr * 16 + fr;
          int cb2 = wc * 128 + nc * 32 + fq * 8;     // byte offset of 4 bf16 cols
          int byte = r * 512 + (cb2 ^ ((r & 7) << 4));
          union { __bf16 h[4]; unsigned long long u; } res, w2;
          res.u = *(unsigned long long*)(act + byte);
          float o0 = acc[nr][nc][0] + b4.x;
          float o1 = acc[nr][nc][1] + b4.y;
          float o2 = acc[nr][nc][2] + b4.z;
          float o3 = acc[nr][nc][3] + b4.w;
          if (L < 3) { o0 = gelu_erf(o0); o1 = gelu_erf(o1);
                       o2 = gelu_erf(o2); o3 = gelu_erf(o3); }
          w2.h[0] = (__bf16)((float)res.h[0] + o0);
          w2.h[1] = (__bf16)((float)res.h[1] + o1);
          w2.h[2] = (__bf16)((float)res.h[2] + o2);
          w2.h[3] = (__bf16)((float)res.h[3] + o3);
          if (VARIANT == 1 && L == 3) {
            *(unsigned long long*)((char*)bout + ((row0 + r) * 512 + cb2)) = w2.u;
          } else {
            *(unsigned long long*)(act + byte) = w2.u;
          }
        }
      }
      if (L != NL - 1) __syncthreads();
    }
  }
}

// ---------------- softmax-over-N merge ----------------
__global__ void softmax_merge(const float* __restrict__ pm, const float* __restrict__ ps,
                              float* __restrict__ Mf, float* __restrict__ Sf) {
  int b = blockIdx.x, t = threadIdx.x;
  const float* pmb = pm + (size_t)b * 512 * 256;
  const float* psb = ps + (size_t)b * 512 * 256;
  float m = -3.0e38f, s = 0.f;
  for (int c = 0; c < 512; ++c) {
    float m2 = pmb[c * 256 + t];
    float s2 = psb[c * 256 + t];
    float mn = fmaxf(m, m2);
    s = s * __expf(m - mn) + s2 * __expf(m2 - mn);
    m = mn;
  }
  Mf[b * 256 + t] = m;
  Sf[b * 256 + t] = 1.f / s;
}

// ---------------- z = enc @ v (partials over n-chunks) ----------------
__global__ __launch_bounds__(256) void z_partial_mfma(
    const float* __restrict__ mixed, const BF16* __restrict__ v,
    const float* __restrict__ Mf, float* __restrict__ zpart) {
  int ci = blockIdx.x;                 // B*64 blocks, 512 rows each
  int b = ci >> 6, ch = ci & 63;
  int tid = threadIdx.x, wid = tid >> 6, lane = tid & 63;
  int l31 = lane & 31, kh = lane >> 5;
  size_t n0 = (size_t)b * 32768 + ch * 512;
  for (int hi = 0; hi < 2; ++hi) {
    int h = wid * 2 + hi;
    int col = h * 32 + l31;
    float Mp = Mf[b * 256 + col];
    f32x16 acc;
#pragma unroll
    for (int r = 0; r < 16; ++r) acc[r] = 0.f;
    for (int s = 0; s < 32; ++s) {
      bf16x8 ea, vb;
      size_t nbase = n0 + s * 16 + kh * 8;
#pragma unroll
      for (int j = 0; j < 8; ++j) {
        float x = __expf(mixed[(nbase + j) * 256 + col] - Mp);
        ea[j] = (__bf16)x;
        vb[j] = *(const __bf16*)&v[(nbase + j) * 256 + col];
      }
      acc = __builtin_amdgcn_mfma_f32_32x32x16_bf16(ea, vb, acc, 0, 0, 0);
    }
    float* zp = zpart + (size_t)ci * 8192 + h * 1024;
#pragma unroll
    for (int reg = 0; reg < 16; ++reg) {
      int m = (reg & 3) + 8 * (reg >> 2) + 4 * kh;
      zp[m * 32 + l31] = acc[reg];
    }
  }
}

__global__ void z_merge(const float* __restrict__ zpart, const float* __restrict__ Sf,
                        float* __restrict__ z) {
  int i = blockIdx.x * 256 + threadIdx.x;   // [0, 4*8192)
  int b = i >> 13, j = i & 8191;
  int p = j >> 5;                           // h*32 + m
  float s = 0.f;
  for (int c = 0; c < 64; ++c) s += zpart[(size_t)(b * 64 + c) * 8192 + j];
  z[i] = s * Sf[b * 256 + p];
}

// ---------------- o = dec^T @ z ----------------
__global__ __launch_bounds__(256) void decode_o_mfma(
    const float* __restrict__ mixed, const float* __restrict__ z,
    BF16* __restrict__ o) {
  int ci = blockIdx.x;
  int b = ci >> 6, ch = ci & 63;
  int tid = threadIdx.x, wid = tid >> 6, lane = tid & 63;
  int l31 = lane & 31, kh = lane >> 5;
  size_t rowbase = (size_t)b * 32768 + ch * 512;
  for (int hi = 0; hi < 2; ++hi) {
    int h = wid * 2 + hi;
    bf16x8 zf[2];
#pragma unroll
    for (int ks = 0; ks < 2; ++ks)
#pragma unroll
      for (int j = 0; j < 8; ++j)
        zf[ks][j] = (__bf16)z[b * 8192 + h * 1024 + (ks * 16 + kh * 8 + j) * 32 + l31];
    for (int s = 0; s < 16; ++s) {
      size_t n = rowbase + s * 32 + l31;
      const float* mrow = mixed + n * 256 + h * 32;
      float xv[16];
#pragma unroll
      for (int ks = 0; ks < 2; ++ks) {
        float4 a  = *(const float4*)(mrow + ks * 16 + kh * 8);
        float4 c4 = *(const float4*)(mrow + ks * 16 + kh * 8 + 4);
        xv[ks * 8 + 0] = a.x;  xv[ks * 8 + 1] = a.y;  xv[ks * 8 + 2] = a.z;  xv[ks * 8 + 3] = a.w;
        xv[ks * 8 + 4] = c4.x; xv[ks * 8 + 5] = c4.y; xv[ks * 8 + 6] = c4.z; xv[ks * 8 + 7] = c4.w;
      }
      float mx = xv[0];
#pragma unroll
      for (int i = 1; i < 16; ++i) mx = fmaxf(mx, xv[i]);
      mx = fmaxf(mx, __shfl_xor(mx, 32));
      float sm = 0.f, ev[16];
#pragma unroll
      for (int i = 0; i < 16; ++i) { ev[i] = __expf(xv[i] - mx); sm += ev[i]; }
      sm += __shfl_xor(sm, 32);
      float inv = 1.f / sm;
      bf16x8 af[2];
#pragma unroll
      for (int ks = 0; ks < 2; ++ks)
#pragma unroll
        for (int j = 0; j < 8; ++j) af[ks][j] = (__bf16)(ev[ks * 8 + j] * inv);
      f32x16 acc;
#pragma unroll
      for (int r = 0; r < 16; ++r) acc[r] = 0.f;
      acc = __builtin_amdgcn_mfma_f32_32x32x16_bf16(af[0], zf[0], acc, 0, 0, 0);
      acc = __builtin_amdgcn_mfma_f32_32x32x16_bf16(af[1], zf[1], acc, 0, 0, 0);
#pragma unroll
      for (int reg = 0; reg < 16; ++reg) {
        int nr = (reg & 3) + 8 * (reg >> 2) + 4 * kh;
        o[(rowbase + s * 32 + nr) * 256 + h * 32 + l31] = __float2bfloat16(acc[reg]);
      }
    }
  }
}

// ---------------- launch ----------------
extern "C" void kernel_launch(void* const* d_in, const int* in_sizes, int n_in,
                              void* d_out, int out_size, void* d_ws, size_t ws_size,
                              hipStream_t stream) {
  const float* x     = (const float*)d_in[0];
  const float* lq    = (const float*)d_in[1];
  const float* kfc1b = (const float*)d_in[3];
  const float* kfcsb = (const float*)d_in[5];
  const float* kfc2b = (const float*)d_in[7];
  const float* vfc1b = (const float*)d_in[9];
  const float* vfcsb = (const float*)d_in[11];
  const float* vfc2b = (const float*)d_in[13];
  const float* mixw  = (const float*)d_in[14];
  const float* outb  = (const float*)d_in[16];

  const int R = in_sizes[0] / 256;          // 131072 rows (B*N)

  char* ws = (char*)d_ws;
  BF16*  v     = (BF16*)(ws);                    // 67,108,864 B
  BF16*  o     = (BF16*)(ws + 67108864);         // 67,108,864 B
  BF16*  wbf   = (BF16*)(ws + 134217728);        //  1,179,648 B
  BF16*  wt    = (BF16*)(ws + 135397376);        //    131,072 B
  float* pm    = (float*)(ws + 135528448);       //  2,097,152 B
  float* ps    = (float*)(ws + 137625600);       //  2,097,152 B
  float* Mf    = (float*)(ws + 139722752);       //      4,096 B
  float* Sf    = (float*)(ws + 139726848);       //      4,096 B
  float* zpart = (float*)(ws + 139730944);       //  8,388,608 B
  float* z     = (float*)(ws + 148119552);       //    131,072 B
  float* mixed = (float*)d_out;                  // d_out doubles as mixed (f32)

  // prep
  WPtrs wp = {{(const float*)d_in[2], (const float*)d_in[4], (const float*)d_in[4] + 65536,
               (const float*)d_in[6], (const float*)d_in[8], (const float*)d_in[10],
               (const float*)d_in[10] + 65536, (const float*)d_in[12], (const float*)d_in[15]}};
  cast_w_kernel<<<2304, 256, 0, stream>>>(wp, wbf);
  build_wtilde<<<256, 256, 0, stream>>>(mixw, lq, wt);

  const int G = R / 64;   // 2048

  // F1: k-MLP + mixed + stats
  FArgs a1;
  a1.w[0] = wbf + 0;      a1.b[0] = kfc1b;
  a1.w[1] = wbf + 65536;  a1.b[1] = kfcsb;
  a1.w[2] = wbf + 131072; a1.b[2] = kfcsb + 256;
  a1.w[3] = wbf + 196608; a1.b[3] = kfc2b;
  a1.w[4] = wt;           a1.b[4] = nullptr;
  fused_mlp<0><<<G, 256, 0, stream>>>(x, nullptr, a1, mixed, nullptr, pm, ps);

  // F2: v-MLP
  FArgs a2;
  a2.w[0] = wbf + 262144; a2.b[0] = vfc1b;
  a2.w[1] = wbf + 327680; a2.b[1] = vfcsb;
  a2.w[2] = wbf + 393216; a2.b[2] = vfcsb + 256;
  a2.w[3] = wbf + 458752; a2.b[3] = vfc2b;
  a2.w[4] = nullptr;      a2.b[4] = nullptr;
  fused_mlp<1><<<G, 256, 0, stream>>>(x, nullptr, a2, nullptr, v, nullptr, nullptr);

  // softmax-over-N merge
  softmax_merge<<<4, 256, 0, stream>>>(pm, ps, Mf, Sf);

  // z = enc @ v
  z_partial_mfma<<<256, 256, 0, stream>>>(mixed, v, Mf, zpart);
  z_merge<<<128, 256, 0, stream>>>(zpart, Sf, z);

  // o = dec^T @ z
  decode_o_mfma<<<256, 256, 0, stream>>>(mixed, z, o);

  // final: out = o @ out_w^T + out_b  (f32 into d_out, overwrites mixed)
  FArgs a3;
  a3.w[0] = wbf + 524288; a3.b[0] = outb;
  for (int i = 1; i < 5; ++i) { a3.w[i] = nullptr; a3.b[i] = nullptr; }
  fused_mlp<2><<<G, 256, 0, stream>>>(nullptr, o, a3, (float*)d_out, nullptr, nullptr, nullptr);
}

// Round 6
// 520.943 us; speedup vs baseline: 1.8804x; 1.1266x over previous
//
#include <hip/hip_runtime.h>
#include <hip/hip_bf16.h>
#include <math.h>

#define BF16 __hip_bfloat16

typedef __bf16 bf16x8 __attribute__((ext_vector_type(8)));
typedef float  f32x4  __attribute__((ext_vector_type(4)));
typedef float  f32x16 __attribute__((ext_vector_type(16)));
typedef int    i32x4  __attribute__((ext_vector_type(4)));

// branch-free erf (Abramowitz-Stegun 7.1.26, |err| < 1.5e-7)
__device__ inline float gelu_erf(float x) {
  float xs = x * 0.70710678118654752f;
  float a = fabsf(xs);
  float t = __builtin_amdgcn_rcpf(1.0f + 0.3275911f * a);
  float p = 1.061405429f;
  p = p * t - 1.453152027f;
  p = p * t + 1.421413741f;
  p = p * t - 0.284496736f;
  p = p * t + 0.254829592f;
  float e = __expf(-a * a);
  float y = 1.0f - p * t * e;
  float s = copysignf(y, xs);
  return 0.5f * x * (1.0f + s);
}

__device__ inline bf16x8 asbf8(i32x4 v) { union { i32x4 i; bf16x8 b; } u; u.i = v; return u.b; }

__device__ inline i32x4 aload16(const char* p) {
  i32x4 d;
  asm volatile("global_load_dwordx4 %0, %1, off" : "=v"(d) : "v"(p));
  return d;
}

template <int N> __device__ inline void vmwait() {
  if constexpr (N == 0)      asm volatile("s_waitcnt vmcnt(0)" ::: "memory");
  else if constexpr (N == 4) asm volatile("s_waitcnt vmcnt(4)" ::: "memory");
  else                       asm volatile("s_waitcnt vmcnt(8)" ::: "memory");
  __builtin_amdgcn_sched_barrier(0);
}

struct WPtrs { const float* p[9]; };
struct FArgs { const BF16* w[5]; const float* b[5]; };

// ---------------- small prep kernels ----------------
// Weights in MFMA-fragment order: elem = W[wc*64+nc*16+fr][kt*32+fq*8+e],
// flat dst = wc*16384 + nc*4096 + kt*512 + (fq*16+fr)*8 + e   (wc: 2 BITS, 4 waves)
// In-kernel: wave wc's fragment (nc,kt) is 1024 contiguous bytes (lane*16B).
__global__ void cast_w_kernel(WPtrs wp, BF16* __restrict__ out) {
  int i = blockIdx.x * 256 + threadIdx.x;   // < 9*65536
  int seg = i >> 16, d = i & 65535;
  int e = d & 7, lane = (d >> 3) & 63, kt = (d >> 9) & 7;
  int nc = (d >> 12) & 3, wc = (d >> 14) & 3;          // <-- was &1: bug, half the matrix garbage
  int fr = lane & 15, fq = lane >> 4;
  int row = wc * 64 + nc * 16 + fr, col = kt * 32 + fq * 8 + e;
  out[i] = __float2bfloat16(wp.p[seg][row * 256 + col]);
}

// W~[p, h*32+d] = sum_j mix_w[p, h*32+j] * latent_q[h*32+j, d], fragment-ordered
__global__ void build_wtilde(const float* __restrict__ mixw, const float* __restrict__ lq,
                             BF16* __restrict__ wt) {
  int p = blockIdx.x, c = threadIdx.x;
  int h = c >> 5, d = c & 31;
  float s = 0.f;
#pragma unroll
  for (int j = 0; j < 32; ++j)
    s += mixw[p * 256 + h * 32 + j] * lq[(h * 32 + j) * 32 + d];
  int wc = p >> 6, nc = (p >> 4) & 3, fr = p & 15;
  int kt = c >> 5, fq = (c >> 3) & 3, e = c & 7;
  int dst = ((((wc * 4 + nc) * 8 + kt) * 64) + (fq * 16 + fr)) * 8 + e;
  wt[dst] = __float2bfloat16(s);
}

// ---------------- fused resident-tile MLP helpers ----------------
__device__ inline void issue4(i32x4 (&buf)[4], const char* wlane, int kt) {
#pragma unroll
  for (int nc = 0; nc < 4; ++nc)
    buf[nc] = aload16(wlane + (nc * 8 + kt) * 1024);
}

__device__ inline void loada4(bf16x8 (&dst)[4], const char* act, int kt, int fr, int fq) {
#pragma unroll
  for (int nr = 0; nr < 4; ++nr) {
    int r = nr * 16 + fr;
    dst[nr] = *(const bf16x8*)(act + r * 512 + ((kt * 64 + fq * 16) ^ ((r & 7) << 4)));
  }
}

__device__ inline void mfma16w(f32x4 (&acc)[4][4], const i32x4 (&wbuf)[4], const bf16x8 (&af)[4]) {
#pragma unroll
  for (int nr = 0; nr < 4; ++nr)
#pragma unroll
    for (int nc = 0; nc < 4; ++nc)
      acc[nr][nc] = __builtin_amdgcn_mfma_f32_16x16x32_bf16(asbf8(wbuf[nc]), af[nr], acc[nr][nc], 0, 0, 0);
}

// ---------------- fused resident-tile MLP ----------------
// VARIANT 0: k-MLP(4 layers) + mixed(=k@Wt^T, f32 out) + softmax-N partial stats
// VARIANT 1: v-MLP(4 layers) -> bf16 global
// VARIANT 2: final projection (1 layer, bias, f32 out)
// act tile: 64 rows x 256 cols bf16 (32KB), XOR-swizzled (byte ^= (r&7)<<4)
// 4 waves split 256 output cols (64 each); per-wave acc[4][4].
// K-loop: inline-asm global_load_dwordx4 + counted vmcnt (12 loads in flight,
// wait vmcnt(8)) so the compiler cannot sink the prefetch. Weights are in
// fragment order -> each load is a fully-coalesced 1024B wave burst.
template <int VARIANT>
__global__ __launch_bounds__(256, 3) void fused_mlp(
    const float* __restrict__ xin, const BF16* __restrict__ oin, FArgs args,
    float* __restrict__ fout, BF16* __restrict__ bout,
    float* __restrict__ pm, float* __restrict__ ps) {
  __shared__ __align__(16) char act[64 * 512];
  const int tid = threadIdx.x;
  const int blk = blockIdx.x;
  const int wc = tid >> 6, lane = tid & 63;
  const int fr = lane & 15, fq = lane >> 4;
  const size_t row0 = (size_t)blk * 64;

  // ---- stage input tile into swizzled LDS ----
  if (VARIANT != 2) {
    const float* xg = xin + row0 * 256;
#pragma unroll
    for (int rep = 0; rep < 16; ++rep) {
      int i = rep * 256 + tid;               // float4 index in tile (4096 total)
      int r = i >> 6, c4 = (i & 63) << 2;
      float4 v = *(const float4*)(xg + r * 256 + c4);
      union { __bf16 h[4]; unsigned long long u; } p;
      p.h[0] = (__bf16)v.x; p.h[1] = (__bf16)v.y;
      p.h[2] = (__bf16)v.z; p.h[3] = (__bf16)v.w;
      int byte = r * 512 + ((c4 * 2) ^ ((r & 7) << 4));
      *(unsigned long long*)(act + byte) = p.u;
    }
  } else {
    const BF16* og = oin + row0 * 256;
#pragma unroll
    for (int rep = 0; rep < 8; ++rep) {
      int i = rep * 256 + tid;               // 16B granule index (2048 total)
      int r = i >> 5, g = i & 31;
      uint4 v = *(const uint4*)(og + r * 256 + g * 8);
      int byte = r * 512 + ((g * 16) ^ ((r & 7) << 4));
      *(uint4*)(act + byte) = v;
    }
  }
  __syncthreads();

  const int NL = (VARIANT == 0) ? 5 : (VARIANT == 1 ? 4 : 1);
#pragma unroll 1
  for (int L = 0; L < NL; ++L) {
    const char* wlane = (const char*)args.w[L] + (size_t)(wc * 2048 + lane) * 16;
    f32x4 acc[4][4];
#pragma unroll
    for (int nr = 0; nr < 4; ++nr)
#pragma unroll
      for (int nc = 0; nc < 4; ++nc)
#pragma unroll
        for (int j = 0; j < 4; ++j) acc[nr][nc][j] = 0.f;

    {
      i32x4 wb0[4], wb1[4], wb2[4];
      bf16x8 afA[4], afB[4];
      issue4(wb0, wlane, 0);
      issue4(wb1, wlane, 1);
      loada4(afA, act, 0, fr, fq);
      // kt0
      issue4(wb2, wlane, 2); loada4(afB, act, 1, fr, fq);
      vmwait<8>(); mfma16w(acc, wb0, afA);
      // kt1
      issue4(wb0, wlane, 3); loada4(afA, act, 2, fr, fq);
      vmwait<8>(); mfma16w(acc, wb1, afB);
      // kt2
      issue4(wb1, wlane, 4); loada4(afB, act, 3, fr, fq);
      vmwait<8>(); mfma16w(acc, wb2, afA);
      // kt3
      issue4(wb2, wlane, 5); loada4(afA, act, 4, fr, fq);
      vmwait<8>(); mfma16w(acc, wb0, afB);
      // kt4
      issue4(wb0, wlane, 6); loada4(afB, act, 5, fr, fq);
      vmwait<8>(); mfma16w(acc, wb1, afA);
      // kt5
      issue4(wb1, wlane, 7); loada4(afA, act, 6, fr, fq);
      vmwait<8>(); mfma16w(acc, wb2, afB);
      // kt6
      loada4(afB, act, 7, fr, fq);
      vmwait<4>(); mfma16w(acc, wb0, afA);
      // kt7
      vmwait<0>(); mfma16w(acc, wb1, afB);
    }
    __syncthreads();   // all act reads done before any epilogue write

    if (VARIANT == 0 && L == 4) {
      // mixed epilogue: f32 global + per-column (over 64 rows) max/sumexp partials
      float* mg = fout + row0 * 256;
#pragma unroll
      for (int nc = 0; nc < 4; ++nc) {
#pragma unroll
        for (int nr = 0; nr < 4; ++nr) {
          float4 st = { acc[nr][nc][0], acc[nr][nc][1], acc[nr][nc][2], acc[nr][nc][3] };
          *(float4*)(mg + (size_t)(nr * 16 + fr) * 256 + wc * 64 + nc * 16 + fq * 4) = st;
        }
        float mx[4], sm[4];
#pragma unroll
        for (int jj = 0; jj < 4; ++jj) {
          float m0 = fmaxf(fmaxf(acc[0][nc][jj], acc[1][nc][jj]),
                           fmaxf(acc[2][nc][jj], acc[3][nc][jj]));
#pragma unroll
          for (int d = 1; d < 16; d <<= 1) m0 = fmaxf(m0, __shfl_xor(m0, d));
          float s0 = 0.f;
#pragma unroll
          for (int nr = 0; nr < 4; ++nr) s0 += __expf(acc[nr][nc][jj] - m0);
#pragma unroll
          for (int d = 1; d < 16; d <<= 1) s0 += __shfl_xor(s0, d);
          mx[jj] = m0; sm[jj] = s0;
        }
        if (fr == 0) {
          int col = wc * 64 + nc * 16 + fq * 4;
          *(float4*)(pm + (size_t)blk * 256 + col) = {mx[0], mx[1], mx[2], mx[3]};
          *(float4*)(ps + (size_t)blk * 256 + col) = {sm[0], sm[1], sm[2], sm[3]};
        }
      }
    } else if (VARIANT == 2) {
      float* og = fout + row0 * 256;
#pragma unroll
      for (int nc = 0; nc < 4; ++nc) {
        float4 b4 = *(const float4*)(args.b[0] + wc * 64 + nc * 16 + fq * 4);
#pragma unroll
        for (int nr = 0; nr < 4; ++nr) {
          float4 st = { acc[nr][nc][0] + b4.x, acc[nr][nc][1] + b4.y,
                        acc[nr][nc][2] + b4.z, acc[nr][nc][3] + b4.w };
          *(float4*)(og + (size_t)(nr * 16 + fr) * 256 + wc * 64 + nc * 16 + fq * 4) = st;
        }
      }
    } else {
      // MLP layer epilogue: bias (+gelu for L<3) + residual; write LDS (or v to global)
      const float* bb = args.b[L];
#pragma unroll
      for (int nc = 0; nc < 4; ++nc) {
        float4 b4 = *(const float4*)(bb + wc * 64 + nc * 16 + fq * 4);
#pragma unroll
        for (int nr = 0; nr < 4; ++nr) {
          int r = nr * 16 + fr;
          int cb2 = wc * 128 + nc * 32 + fq * 8;     // byte offset of 4 bf16 cols
          int byte = r * 512 + (cb2 ^ ((r & 7) << 4));
          union { __bf16 h[4]; unsigned long long u; } res, w2;
          res.u = *(unsigned long long*)(act + byte);
          float o0 = acc[nr][nc][0] + b4.x;
          float o1 = acc[nr][nc][1] + b4.y;
          float o2 = acc[nr][nc][2] + b4.z;
          float o3 = acc[nr][nc][3] + b4.w;
          if (L < 3) { o0 = gelu_erf(o0); o1 = gelu_erf(o1);
                       o2 = gelu_erf(o2); o3 = gelu_erf(o3); }
          w2.h[0] = (__bf16)((float)res.h[0] + o0);
          w2.h[1] = (__bf16)((float)res.h[1] + o1);
          w2.h[2] = (__bf16)((float)res.h[2] + o2);
          w2.h[3] = (__bf16)((float)res.h[3] + o3);
          if (VARIANT == 1 && L == 3) {
            *(unsigned long long*)((char*)bout + ((row0 + r) * 512 + cb2)) = w2.u;
          } else {
            *(unsigned long long*)(act + byte) = w2.u;
          }
        }
      }
      if (L != NL - 1) __syncthreads();
    }
  }
}

// ---------------- softmax-over-N merge ----------------
__global__ void softmax_merge(const float* __restrict__ pm, const float* __restrict__ ps,
                              float* __restrict__ Mf, float* __restrict__ Sf) {
  int b = blockIdx.x, t = threadIdx.x;
  const float* pmb = pm + (size_t)b * 512 * 256;
  const float* psb = ps + (size_t)b * 512 * 256;
  float m = -3.0e38f, s = 0.f;
  for (int c = 0; c < 512; ++c) {
    float m2 = pmb[c * 256 + t];
    float s2 = psb[c * 256 + t];
    float mn = fmaxf(m, m2);
    s = s * __expf(m - mn) + s2 * __expf(m2 - mn);
    m = mn;
  }
  Mf[b * 256 + t] = m;
  Sf[b * 256 + t] = 1.f / s;
}

// ---------------- z = enc @ v (partials over n-chunks) ----------------
__global__ __launch_bounds__(256) void z_partial_mfma(
    const float* __restrict__ mixed, const BF16* __restrict__ v,
    const float* __restrict__ Mf, float* __restrict__ zpart) {
  int ci = blockIdx.x;                 // B*128 blocks, 256 rows each
  int b = ci >> 7, ch = ci & 127;
  int tid = threadIdx.x, wid = tid >> 6, lane = tid & 63;
  int l31 = lane & 31, kh = lane >> 5;
  size_t n0 = (size_t)b * 32768 + ch * 256;
  for (int hi = 0; hi < 2; ++hi) {
    int h = wid * 2 + hi;
    int col = h * 32 + l31;
    float Mp = Mf[b * 256 + col];
    f32x16 acc;
#pragma unroll
    for (int r = 0; r < 16; ++r) acc[r] = 0.f;
    for (int s = 0; s < 16; ++s) {
      bf16x8 ea, vb;
      size_t nbase = n0 + s * 16 + kh * 8;
#pragma unroll
      for (int j = 0; j < 8; ++j) {
        float x = __expf(mixed[(nbase + j) * 256 + col] - Mp);
        ea[j] = (__bf16)x;
        vb[j] = *(const __bf16*)&v[(nbase + j) * 256 + col];
      }
      acc = __builtin_amdgcn_mfma_f32_32x32x16_bf16(ea, vb, acc, 0, 0, 0);
    }
    float* zp = zpart + (size_t)ci * 8192 + h * 1024;
#pragma unroll
    for (int reg = 0; reg < 16; ++reg) {
      int m = (reg & 3) + 8 * (reg >> 2) + 4 * kh;
      zp[m * 32 + l31] = acc[reg];
    }
  }
}

__global__ void z_merge(const float* __restrict__ zpart, const float* __restrict__ Sf,
                        float* __restrict__ z) {
  int i = blockIdx.x * 256 + threadIdx.x;   // [0, 4*8192)
  int b = i >> 13, j = i & 8191;
  int p = j >> 5;                           // h*32 + m
  float s = 0.f;
  for (int c = 0; c < 128; ++c) s += zpart[(size_t)(b * 128 + c) * 8192 + j];
  z[i] = s * Sf[b * 256 + p];
}

// ---------------- o = dec^T @ z ----------------
__global__ __launch_bounds__(256) void decode_o_mfma(
    const float* __restrict__ mixed, const float* __restrict__ z,
    BF16* __restrict__ o) {
  int ci = blockIdx.x;                 // B*128 blocks, 256 rows each
  int b = ci >> 7, ch = ci & 127;
  int tid = threadIdx.x, wid = tid >> 6, lane = tid & 63;
  int l31 = lane & 31, kh = lane >> 5;
  size_t rowbase = (size_t)b * 32768 + ch * 256;
  for (int hi = 0; hi < 2; ++hi) {
    int h = wid * 2 + hi;
    bf16x8 zf[2];
#pragma unroll
    for (int ks = 0; ks < 2; ++ks)
#pragma unroll
      for (int j = 0; j < 8; ++j)
        zf[ks][j] = (__bf16)z[b * 8192 + h * 1024 + (ks * 16 + kh * 8 + j) * 32 + l31];
    for (int s = 0; s < 8; ++s) {
      size_t n = rowbase + s * 32 + l31;
      const float* mrow = mixed + n * 256 + h * 32;
      float xv[16];
#pragma unroll
      for (int ks = 0; ks < 2; ++ks) {
        float4 a  = *(const float4*)(mrow + ks * 16 + kh * 8);
        float4 c4 = *(const float4*)(mrow + ks * 16 + kh * 8 + 4);
        xv[ks * 8 + 0] = a.x;  xv[ks * 8 + 1] = a.y;  xv[ks * 8 + 2] = a.z;  xv[ks * 8 + 3] = a.w;
        xv[ks * 8 + 4] = c4.x; xv[ks * 8 + 5] = c4.y; xv[ks * 8 + 6] = c4.z; xv[ks * 8 + 7] = c4.w;
      }
      float mx = xv[0];
#pragma unroll
      for (int i = 1; i < 16; ++i) mx = fmaxf(mx, xv[i]);
      mx = fmaxf(mx, __shfl_xor(mx, 32));
      float sm = 0.f, ev[16];
#pragma unroll
      for (int i = 0; i < 16; ++i) { ev[i] = __expf(xv[i] - mx); sm += ev[i]; }
      sm += __shfl_xor(sm, 32);
      float inv = 1.f / sm;
      bf16x8 af[2];
#pragma unroll
      for (int ks = 0; ks < 2; ++ks)
#pragma unroll
        for (int j = 0; j < 8; ++j) af[ks][j] = (__bf16)(ev[ks * 8 + j] * inv);
      f32x16 acc;
#pragma unroll
      for (int r = 0; r < 16; ++r) acc[r] = 0.f;
      acc = __builtin_amdgcn_mfma_f32_32x32x16_bf16(af[0], zf[0], acc, 0, 0, 0);
      acc = __builtin_amdgcn_mfma_f32_32x32x16_bf16(af[1], zf[1], acc, 0, 0, 0);
#pragma unroll
      for (int reg = 0; reg < 16; ++reg) {
        int nr = (reg & 3) + 8 * (reg >> 2) + 4 * kh;
        o[(rowbase + s * 32 + nr) * 256 + h * 32 + l31] = __float2bfloat16(acc[reg]);
      }
    }
  }
}

// ---------------- launch ----------------
extern "C" void kernel_launch(void* const* d_in, const int* in_sizes, int n_in,
                              void* d_out, int out_size, void* d_ws, size_t ws_size,
                              hipStream_t stream) {
  const float* x     = (const float*)d_in[0];
  const float* lq    = (const float*)d_in[1];
  const float* kfc1b = (const float*)d_in[3];
  const float* kfcsb = (const float*)d_in[5];
  const float* kfc2b = (const float*)d_in[7];
  const float* vfc1b = (const float*)d_in[9];
  const float* vfcsb = (const float*)d_in[11];
  const float* vfc2b = (const float*)d_in[13];
  const float* mixw  = (const float*)d_in[14];
  const float* outb  = (const float*)d_in[16];

  const int R = in_sizes[0] / 256;          // 131072 rows (B*N)

  char* ws = (char*)d_ws;
  BF16*  v     = (BF16*)(ws);                    // 67,108,864 B
  BF16*  o     = (BF16*)(ws + 67108864);         // 67,108,864 B
  BF16*  wbf   = (BF16*)(ws + 134217728);        //  1,179,648 B
  BF16*  wt    = (BF16*)(ws + 135397376);        //    131,072 B
  float* pm    = (float*)(ws + 135528448);       //  2,097,152 B
  float* ps    = (float*)(ws + 137625600);       //  2,097,152 B
  float* Mf    = (float*)(ws + 139722752);       //      4,096 B
  float* Sf    = (float*)(ws + 139726848);       //      4,096 B
  float* zpart = (float*)(ws + 139730944);       // 16,777,216 B
  float* z     = (float*)(ws + 156508160);       //    131,072 B
  float* mixed = (float*)d_out;                  // d_out doubles as mixed (f32)

  // prep
  WPtrs wp = {{(const float*)d_in[2], (const float*)d_in[4], (const float*)d_in[4] + 65536,
               (const float*)d_in[6], (const float*)d_in[8], (const float*)d_in[10],
               (const float*)d_in[10] + 65536, (const float*)d_in[12], (const float*)d_in[15]}};
  cast_w_kernel<<<2304, 256, 0, stream>>>(wp, wbf);
  build_wtilde<<<256, 256, 0, stream>>>(mixw, lq, wt);

  const int G = R / 64;   // 2048

  // F1: k-MLP + mixed + stats
  FArgs a1;
  a1.w[0] = wbf + 0;      a1.b[0] = kfc1b;
  a1.w[1] = wbf + 65536;  a1.b[1] = kfcsb;
  a1.w[2] = wbf + 131072; a1.b[2] = kfcsb + 256;
  a1.w[3] = wbf + 196608; a1.b[3] = kfc2b;
  a1.w[4] = wt;           a1.b[4] = nullptr;
  fused_mlp<0><<<G, 256, 0, stream>>>(x, nullptr, a1, mixed, nullptr, pm, ps);

  // F2: v-MLP
  FArgs a2;
  a2.w[0] = wbf + 262144; a2.b[0] = vfc1b;
  a2.w[1] = wbf + 327680; a2.b[1] = vfcsb;
  a2.w[2] = wbf + 393216; a2.b[2] = vfcsb + 256;
  a2.w[3] = wbf + 458752; a2.b[3] = vfc2b;
  a2.w[4] = nullptr;      a2.b[4] = nullptr;
  fused_mlp<1><<<G, 256, 0, stream>>>(x, nullptr, a2, nullptr, v, nullptr, nullptr);

  // softmax-over-N merge
  softmax_merge<<<4, 256, 0, stream>>>(pm, ps, Mf, Sf);

  // z = enc @ v
  z_partial_mfma<<<512, 256, 0, stream>>>(mixed, v, Mf, zpart);
  z_merge<<<128, 256, 0, stream>>>(zpart, Sf, z);

  // o = dec^T @ z
  decode_o_mfma<<<512, 256, 0, stream>>>(mixed, z, o);

  // final: out = o @ out_w^T + out_b  (f32 into d_out, overwrites mixed)
  FArgs a3;
  a3.w[0] = wbf + 524288; a3.b[0] = outb;
  for (int i = 1; i < 5; ++i) { a3.w[i] = nullptr; a3.b[i] = nullptr; }
  fused_mlp<2><<<G, 256, 0, stream>>>(nullptr, o, a3, (float*)d_out, nullptr, nullptr, nullptr);
}